// Round 7
// baseline (401.171 us; speedup 1.0000x reference)
//
#include <hip/hip_runtime.h>
#include <hip/hip_bf16.h>
#include <cstddef>

#define NNODES 100000
#define NEDGES 1600000
#define CIN 128
#define HID 256
#define ACT 20
#define NGRAPH (NNODES / ACT)
#define BSHIFT 8
#define NB ((NNODES + 255) >> 8)     // 391 buckets of 256 nodes
#define BIN_WGS 512
#define CAP 8192                     // bucket window capacity (mean fill 4096)

typedef __attribute__((ext_vector_type(8))) short short8;
typedef __attribute__((ext_vector_type(4))) float f32x4;

__device__ __forceinline__ unsigned short f2b(float f) {
    unsigned u = __float_as_uint(f);
    u += 0x7FFF + ((u >> 16) & 1);          // round-to-nearest-even
    return (unsigned short)(u >> 16);
}
__device__ __forceinline__ float b2f(unsigned short h) {
    return __uint_as_float(((unsigned)h) << 16);
}

// ---------------- bucketed CSR build (fixed-capacity windows) ----------------
// entries[b*CAP + i] = (src << 8) | (dst & 255); bfill[b] = bucket fill count.

__global__ __launch_bounds__(256) void bin_k(const int* __restrict__ ei,
                                             int* __restrict__ bfill,
                                             unsigned* __restrict__ entries) {
    __shared__ int cnt[NB], base[NB], cur[NB];
    for (int i = threadIdx.x; i < NB; i += 256) { cnt[i] = 0; cur[i] = 0; }
    __syncthreads();
    const int per = NEDGES / BIN_WGS;      // 3125
    const int s = blockIdx.x * per;
    const int e = s + per;
    for (int i = s + threadIdx.x; i < e; i += 256)
        atomicAdd(&cnt[ei[NEDGES + i] >> BSHIFT], 1);
    __syncthreads();
    for (int i = threadIdx.x; i < NB; i += 256)
        base[i] = cnt[i] ? atomicAdd(&bfill[i], cnt[i]) : 0;
    __syncthreads();
    for (int i = s + threadIdx.x; i < e; i += 256) {
        int src = ei[i], dst = ei[NEDGES + i];
        int b = dst >> BSHIFT;
        int r = base[b] + atomicAdd(&cur[b], 1);
        if (r < CAP)
            entries[(size_t)b * CAP + r] = ((unsigned)src << 8) | (unsigned)(dst & 255);
    }
}

// one wg per bucket: count, scan, rowptr2+dinv, scatter into padded csr window
__global__ __launch_bounds__(256) void bucket_build_k(
    const unsigned* __restrict__ entries, const int* __restrict__ bfill,
    int2* __restrict__ rowptr2, int* __restrict__ csr, float* __restrict__ dinv) {
    const int b = blockIdx.x;
    const int count = min(bfill[b], CAP);
    const int node0 = b << BSHIFT;
    const int nn = min(256, NNODES - node0);
    const size_t gbase = (size_t)b * CAP;
    __shared__ int cnt[256], off[256], cur[256];
    const int t = threadIdx.x;
    cnt[t] = 0; cur[t] = 0;
    __syncthreads();
    for (int i = t; i < count; i += 256)
        atomicAdd(&cnt[entries[gbase + i] & 255], 1);
    __syncthreads();
    int lane = t & 63, wid = t >> 6;
    int v = cnt[t];
    int inc = v;
#pragma unroll
    for (int o = 1; o < 64; o <<= 1) {
        int tv = __shfl_up(inc, o, 64);
        if (lane >= o) inc += tv;
    }
    __shared__ int wsum[4];
    if (lane == 63) wsum[wid] = inc;
    __syncthreads();
    int woff = 0;
#pragma unroll
    for (int w = 0; w < 4; ++w) woff += (w < wid) ? wsum[w] : 0;
    int excl = inc + woff - v;
    off[t] = excl;
    if (t < nn) {
        rowptr2[node0 + t] = make_int2((int)gbase + excl, (int)gbase + excl + v);
        dinv[node0 + t] = rsqrtf(1.0f + (float)v);
    }
    __syncthreads();
    for (int i = t; i < count; i += 256) {
        unsigned en = entries[gbase + i];
        int loc = (int)(en & 255);
        int r = atomicAdd(&cur[loc], 1);
        csr[gbase + off[loc] + r] = (int)(en >> 8);
    }
}

// ---------------- weight conversions (single launch) ----------------

__global__ void cvt_w_k(const float* __restrict__ conv_w,
                        const float* __restrict__ lin1_w,
                        const float* __restrict__ lin2_w,
                        unsigned short* __restrict__ wt0,
                        unsigned short* __restrict__ wt1,
                        unsigned short* __restrict__ wt2) {
    int id = blockIdx.x * 256 + threadIdx.x;
    if (id < 16384) {
        int k = id >> 7, n = id & 127;
        wt0[n * 128 + k] = f2b(conv_w[k * 128 + n]);
    } else if (id < 16384 + 32768) {
        int i = id - 16384;
        wt1[i] = f2b(lin1_w[i]);
    } else if (id < 16384 + 32768 + 65536) {
        int i = id - 49152;
        wt2[i] = f2b(lin2_w[i]);
    }
}

// ---------------- MFMA bf16 GEMM for conv (fp32 A in-register cvt) ----------

__global__ __launch_bounds__(256) void mgemm0_k(
    const float* __restrict__ Af, const unsigned short* __restrict__ B,
    const float* __restrict__ dinv, unsigned short* __restrict__ Cout, int M)
{
    const int tid = threadIdx.x;
    const int wid = tid >> 6;
    const int lane = tid & 63;
    const int quad = lane >> 4;
    const int l16 = lane & 15;
    const int bm = blockIdx.x * 128 + (wid >> 1) * 64;
    const int bn = (wid & 1) * 64;

    const short8 zed = {0, 0, 0, 0, 0, 0, 0, 0};
    f32x4 acc[4][4];
#pragma unroll
    for (int i = 0; i < 4; ++i)
#pragma unroll
        for (int j = 0; j < 4; ++j) {
            f32x4 z = {0.f, 0.f, 0.f, 0.f};
            acc[i][j] = z;
        }

#pragma unroll
    for (int k0 = 0; k0 < 128; k0 += 32) {
        const int ka = k0 + quad * 8;
        short8 a[4], b[4];
#pragma unroll
        for (int t = 0; t < 4; ++t) {
            int m = bm + t * 16 + l16;
            short8 av = zed;
            if (m < M) {
                float4 f0 = *reinterpret_cast<const float4*>(Af + (size_t)m * 128 + ka);
                float4 f1 = *reinterpret_cast<const float4*>(Af + (size_t)m * 128 + ka + 4);
                av[0] = (short)f2b(f0.x); av[1] = (short)f2b(f0.y);
                av[2] = (short)f2b(f0.z); av[3] = (short)f2b(f0.w);
                av[4] = (short)f2b(f1.x); av[5] = (short)f2b(f1.y);
                av[6] = (short)f2b(f1.z); av[7] = (short)f2b(f1.w);
            }
            a[t] = av;
            int n = bn + t * 16 + l16;
            b[t] = *reinterpret_cast<const short8*>(B + (size_t)n * 128 + ka);
        }
#pragma unroll
        for (int i = 0; i < 4; ++i)
#pragma unroll
            for (int j = 0; j < 4; ++j)
                acc[i][j] = __builtin_amdgcn_mfma_f32_16x16x32_bf16(a[i], b[j], acc[i][j], 0, 0, 0);
    }

#pragma unroll
    for (int i = 0; i < 4; ++i)
#pragma unroll
        for (int r = 0; r < 4; ++r) {
            int row = bm + i * 16 + quad * 4 + r;
            if (row >= M) continue;
            float dv = dinv[row];
#pragma unroll
            for (int j = 0; j < 4; ++j) {
                int col = bn + j * 16 + l16;
                Cout[(size_t)row * 128 + col] = f2b(acc[i][j][r] * dv);
            }
        }
}

// ---------------- gather v4: 4 rows per wave-load, padded CSR ----------------

__global__ __launch_bounds__(256) void gather_k(
    const int2* __restrict__ rowptr2, const int* __restrict__ csr,
    const unsigned short* __restrict__ xws, const float* __restrict__ dinv,
    const float* __restrict__ x, const float* __restrict__ conv_b,
    unsigned short* __restrict__ h0)
{
    const int node = blockIdx.x * 4 + (threadIdx.x >> 6);
    if (node >= NNODES) return;
    const int lane = threadIdx.x & 63;
    const int sub = lane >> 4;
    const int c16 = lane & 15;

    const int2 se = rowptr2[node];
    const int start = se.x, end = se.y;

    float s[8];
    if (sub == 0) {
        short8 r = *reinterpret_cast<const short8*>(xws + (size_t)node * CIN + c16 * 8);
#pragma unroll
        for (int q = 0; q < 8; ++q) s[q] = b2f((unsigned short)r[q]);
    } else {
#pragma unroll
        for (int q = 0; q < 8; ++q) s[q] = 0.f;
    }

    for (int p = start; p < end; p += 16) {
        short8 r[4];
        int valid[4];
#pragma unroll
        for (int j = 0; j < 4; ++j) {
            int e = p + j * 4 + sub;
            bool a = e < end;
            int idx = a ? csr[e] : node;
            r[j] = *reinterpret_cast<const short8*>(xws + (size_t)idx * CIN + c16 * 8);
            valid[j] = a;
        }
#pragma unroll
        for (int j = 0; j < 4; ++j)
            if (valid[j]) {
#pragma unroll
                for (int q = 0; q < 8; ++q) s[q] += b2f((unsigned short)r[j][q]);
            }
    }

#pragma unroll
    for (int q = 0; q < 8; ++q) {
        s[q] += __shfl_xor(s[q], 16, 64);
        s[q] += __shfl_xor(s[q], 32, 64);
    }

    if (sub == 0) {
        float dvv = dinv[node];
        float4 b0 = *reinterpret_cast<const float4*>(conv_b + c16 * 8);
        float4 b1 = *reinterpret_cast<const float4*>(conv_b + c16 * 8 + 4);
        float4 x0 = *reinterpret_cast<const float4*>(x + (size_t)node * CIN + c16 * 8);
        float4 x1 = *reinterpret_cast<const float4*>(x + (size_t)node * CIN + c16 * 8 + 4);
        float o[8];
        o[0] = fmaxf(s[0] * dvv + b0.x, 0.f) + x0.x;
        o[1] = fmaxf(s[1] * dvv + b0.y, 0.f) + x0.y;
        o[2] = fmaxf(s[2] * dvv + b0.z, 0.f) + x0.z;
        o[3] = fmaxf(s[3] * dvv + b0.w, 0.f) + x0.w;
        o[4] = fmaxf(s[4] * dvv + b1.x, 0.f) + x1.x;
        o[5] = fmaxf(s[5] * dvv + b1.y, 0.f) + x1.y;
        o[6] = fmaxf(s[6] * dvv + b1.z, 0.f) + x1.z;
        o[7] = fmaxf(s[7] * dvv + b1.w, 0.f) + x1.w;
        short8 pk;
#pragma unroll
        for (int q = 0; q < 8; ++q) pk[q] = (short)f2b(o[q]);
        *reinterpret_cast<short8*>(h0 + (size_t)node * CIN + c16 * 8) = pk;
    }
}

// ---------------- out init (harness poisons d_out every call) ----------------

__global__ void init_out_k(float* __restrict__ out, const float* __restrict__ b3) {
    int i = blockIdx.x * 256 + threadIdx.x;
    if (i < NGRAPH) out[i] = b3[0];
}

// ---------------- fused MLP v2: 512 thr, 128 rows/block, swizzled LDS -------
// XOR-swizzled h1 tile: element (row,col) at
//   row*256 + (((col>>3) ^ (row&7))<<3) + (col&7)
// Phase-2 b128 reads hit bank-group (kt*4+quad)^(l16&7): 8 lanes/group = optimal.
// out[row/20] += sum_col relu(h2[row][col]+b2[col]) * w3[col]

__global__ __launch_bounds__(512) void mlp_k(
    const unsigned short* __restrict__ h0, const unsigned short* __restrict__ w1,
    const float* __restrict__ b1, const unsigned short* __restrict__ w2,
    const float* __restrict__ b2, const float* __restrict__ w3,
    float* __restrict__ out)
{
    __shared__ unsigned short h1s[128 * 256];   // 64 KB, swizzled
    const int tid = threadIdx.x;
    const int wv = tid >> 6;          // 0..7
    const int lane = tid & 63;
    const int quad = lane >> 4;
    const int l16 = lane & 15;
    const int mrow0 = (wv >> 2) * 64;           // block-local row tile: 0 / 64
    const int ncol0 = (wv & 3) * 64;            // col tile: 0/64/128/192
    const int bm = blockIdx.x * 128;

    const short8 zed = {0, 0, 0, 0, 0, 0, 0, 0};
    f32x4 acc[4][4];
#pragma unroll
    for (int i = 0; i < 4; ++i)
#pragma unroll
        for (int j = 0; j < 4; ++j) {
            f32x4 z = {0.f, 0.f, 0.f, 0.f};
            acc[i][j] = z;
        }

    // ---- phase 1: h1 = relu(h0 @ W1^T + b1), K=128 ----
#pragma unroll
    for (int kt = 0; kt < 4; ++kt) {
        const int ka = kt * 32 + quad * 8;
        short8 a[4], b[4];
#pragma unroll
        for (int t = 0; t < 4; ++t) {
            int m = bm + mrow0 + t * 16 + l16;
            a[t] = (m < NNODES) ? *reinterpret_cast<const short8*>(h0 + (size_t)m * 128 + ka) : zed;
            int n = ncol0 + t * 16 + l16;
            b[t] = *reinterpret_cast<const short8*>(w1 + (size_t)n * 128 + ka);
        }
#pragma unroll
        for (int i = 0; i < 4; ++i)
#pragma unroll
            for (int j = 0; j < 4; ++j)
                acc[i][j] = __builtin_amdgcn_mfma_f32_16x16x32_bf16(a[i], b[j], acc[i][j], 0, 0, 0);
    }

#pragma unroll
    for (int nt = 0; nt < 4; ++nt) {
        int col = ncol0 + nt * 16 + l16;
        float bv = b1[col];
        int chunk = col >> 3, rem = col & 7;
#pragma unroll
        for (int mt = 0; mt < 4; ++mt)
#pragma unroll
            for (int r = 0; r < 4; ++r) {
                int row = mrow0 + mt * 16 + quad * 4 + r;
                h1s[row * 256 + (((chunk ^ (row & 7)) << 3) | rem)] =
                    f2b(fmaxf(acc[mt][nt][r] + bv, 0.f));
            }
    }
    __syncthreads();

    // ---- phase 2: h2 = relu(h1s @ W2^T + b2), K=256 ----
#pragma unroll
    for (int i = 0; i < 4; ++i)
#pragma unroll
        for (int j = 0; j < 4; ++j) {
            f32x4 z = {0.f, 0.f, 0.f, 0.f};
            acc[i][j] = z;
        }
#pragma unroll
    for (int kt = 0; kt < 8; ++kt) {
        const int ka = kt * 32 + quad * 8;
        const int chunk = ka >> 3;               // kt*4 + quad
        short8 a[4], b[4];
#pragma unroll
        for (int t = 0; t < 4; ++t) {
            int row = mrow0 + t * 16 + l16;
            a[t] = *reinterpret_cast<const short8*>(
                &h1s[row * 256 + ((chunk ^ (row & 7)) << 3)]);
            int n = ncol0 + t * 16 + l16;
            b[t] = *reinterpret_cast<const short8*>(w2 + (size_t)n * 256 + ka);
        }
#pragma unroll
        for (int i = 0; i < 4; ++i)
#pragma unroll
            for (int j = 0; j < 4; ++j)
                acc[i][j] = __builtin_amdgcn_mfma_f32_16x16x32_bf16(a[i], b[j], acc[i][j], 0, 0, 0);
    }

    // ---- fused epilogue: partial w3-dot over this wave's 64 cols ----
    float part[4][4];
#pragma unroll
    for (int mt = 0; mt < 4; ++mt)
#pragma unroll
        for (int r = 0; r < 4; ++r) part[mt][r] = 0.f;
#pragma unroll
    for (int nt = 0; nt < 4; ++nt) {
        int ncol = ncol0 + nt * 16 + l16;
        float bs = b2[ncol];
        float wv3 = w3[ncol];
#pragma unroll
        for (int mt = 0; mt < 4; ++mt)
#pragma unroll
            for (int r = 0; r < 4; ++r)
                part[mt][r] += fmaxf(acc[mt][nt][r] + bs, 0.f) * wv3;
    }
#pragma unroll
    for (int mt = 0; mt < 4; ++mt)
#pragma unroll
        for (int r = 0; r < 4; ++r) {
            float v = part[mt][r];
            v += __shfl_xor(v, 1, 64);
            v += __shfl_xor(v, 2, 64);
            v += __shfl_xor(v, 4, 64);
            v += __shfl_xor(v, 8, 64);
            part[mt][r] = v;
        }
    if (l16 == 0) {
#pragma unroll
        for (int mt = 0; mt < 4; ++mt)
#pragma unroll
            for (int r = 0; r < 4; ++r) {
                int row = bm + mrow0 + mt * 16 + quad * 4 + r;
                if (row < NNODES) atomicAdd(&out[row / ACT], part[mt][r]);
            }
    }
}

// ---------------- launch ----------------

extern "C" void kernel_launch(void* const* d_in, const int* in_sizes, int n_in,
                              void* d_out, int out_size, void* d_ws, size_t ws_size,
                              hipStream_t stream)
{
    const float* x      = (const float*)d_in[0];
    const int*   ei     = (const int*)  d_in[1];
    const float* conv_w = (const float*)d_in[2];
    const float* conv_b = (const float*)d_in[3];
    const float* lin1_w = (const float*)d_in[4];
    const float* lin1_b = (const float*)d_in[5];
    const float* lin2_w = (const float*)d_in[6];
    const float* lin2_b = (const float*)d_in[7];
    const float* lin3_w = (const float*)d_in[8];
    const float* lin3_b = (const float*)d_in[9];
    float* out = (float*)d_out;

    unsigned short* xws     = (unsigned short*)d_ws;
    unsigned short* h0      = xws + (size_t)12800000;
    unsigned*       entries = (unsigned*)(h0 + (size_t)12800000);
    int*            csr     = (int*)(entries + (size_t)NB * CAP);
    int2*           rowptr2 = (int2*)(csr + (size_t)NB * CAP);
    float*          dinv    = (float*)(rowptr2 + NNODES);
    int*            bfill   = (int*)(dinv + NNODES);
    unsigned short* wt0     = (unsigned short*)(bfill + NB + 8);
    unsigned short* wt1     = wt0 + 16384;
    unsigned short* wt2     = wt1 + 32768;

    // CSR build (fixed-capacity bucket windows)
    hipMemsetAsync(bfill, 0, NB * sizeof(int), stream);
    bin_k<<<BIN_WGS, 256, 0, stream>>>(ei, bfill, entries);
    bucket_build_k<<<NB, 256, 0, stream>>>(entries, bfill, rowptr2, csr, dinv);

    // weight conversions (one launch)
    cvt_w_k<<<(114688 + 255) / 256, 256, 0, stream>>>(conv_w, lin1_w, lin2_w, wt0, wt1, wt2);

    // gemm0: xws = (x @ conv_w) * dinv[row]
    mgemm0_k<<<(NNODES + 127) / 128, 256, 0, stream>>>(x, wt0, dinv, xws, NNODES);

    // gather + conv epilogue -> h0 bf16
    gather_k<<<(NNODES + 3) / 4, 256, 0, stream>>>(rowptr2, csr, xws, dinv, x, conv_b, h0);

    // out = b3, then fused MLP accumulates into it
    init_out_k<<<(NGRAPH + 255) / 256, 256, 0, stream>>>(out, lin3_b);

    mlp_k<<<(NNODES + 127) / 128, 512, 0, stream>>>(h0, wt1, lin1_b, wt2, lin2_b, lin3_w, out);
}

// Round 8
// 377.533 us; speedup vs baseline: 1.0626x; 1.0626x over previous
//
#include <hip/hip_runtime.h>
#include <hip/hip_bf16.h>
#include <cstddef>

#define NNODES 100000
#define NEDGES 1600000
#define CIN 128
#define HID 256
#define ACT 20
#define NGRAPH (NNODES / ACT)
#define BSHIFT 8
#define NB ((NNODES + 255) >> 8)     // 391 buckets of 256 nodes
#define BIN_WGS 512
#define CAP 8192                     // bucket window capacity (mean fill 4096)

typedef __attribute__((ext_vector_type(8))) short short8;
typedef __attribute__((ext_vector_type(4))) float f32x4;

__device__ __forceinline__ unsigned short f2b(float f) {
    unsigned u = __float_as_uint(f);
    u += 0x7FFF + ((u >> 16) & 1);          // round-to-nearest-even
    return (unsigned short)(u >> 16);
}
__device__ __forceinline__ float b2f(unsigned short h) {
    return __uint_as_float(((unsigned)h) << 16);
}

// async global->LDS, 16B per lane; HW semantics: wave-uniform LDS base + lane*16
__device__ __forceinline__ void gld16(const void* g, void* l) {
    __builtin_amdgcn_global_load_lds(
        (const __attribute__((address_space(1))) unsigned int*)g,
        (__attribute__((address_space(3))) unsigned int*)l, 16, 0, 0);
}

// ---------------- bucketed CSR build (fixed-capacity windows) ----------------

__global__ __launch_bounds__(256) void bin_k(const int* __restrict__ ei,
                                             int* __restrict__ bfill,
                                             unsigned* __restrict__ entries) {
    __shared__ int cnt[NB], base[NB], cur[NB];
    for (int i = threadIdx.x; i < NB; i += 256) { cnt[i] = 0; cur[i] = 0; }
    __syncthreads();
    const int per = NEDGES / BIN_WGS;      // 3125
    const int s = blockIdx.x * per;
    const int e = s + per;
    for (int i = s + threadIdx.x; i < e; i += 256)
        atomicAdd(&cnt[ei[NEDGES + i] >> BSHIFT], 1);
    __syncthreads();
    for (int i = threadIdx.x; i < NB; i += 256)
        base[i] = cnt[i] ? atomicAdd(&bfill[i], cnt[i]) : 0;
    __syncthreads();
    for (int i = s + threadIdx.x; i < e; i += 256) {
        int src = ei[i], dst = ei[NEDGES + i];
        int b = dst >> BSHIFT;
        int r = base[b] + atomicAdd(&cur[b], 1);
        if (r < CAP)
            entries[(size_t)b * CAP + r] = ((unsigned)src << 8) | (unsigned)(dst & 255);
    }
}

__global__ __launch_bounds__(256) void bucket_build_k(
    const unsigned* __restrict__ entries, const int* __restrict__ bfill,
    int2* __restrict__ rowptr2, int* __restrict__ csr, float* __restrict__ dinv) {
    const int b = blockIdx.x;
    const int count = min(bfill[b], CAP);
    const int node0 = b << BSHIFT;
    const int nn = min(256, NNODES - node0);
    const size_t gbase = (size_t)b * CAP;
    __shared__ int cnt[256], off[256], cur[256];
    const int t = threadIdx.x;
    cnt[t] = 0; cur[t] = 0;
    __syncthreads();
    for (int i = t; i < count; i += 256)
        atomicAdd(&cnt[entries[gbase + i] & 255], 1);
    __syncthreads();
    int lane = t & 63, wid = t >> 6;
    int v = cnt[t];
    int inc = v;
#pragma unroll
    for (int o = 1; o < 64; o <<= 1) {
        int tv = __shfl_up(inc, o, 64);
        if (lane >= o) inc += tv;
    }
    __shared__ int wsum[4];
    if (lane == 63) wsum[wid] = inc;
    __syncthreads();
    int woff = 0;
#pragma unroll
    for (int w = 0; w < 4; ++w) woff += (w < wid) ? wsum[w] : 0;
    int excl = inc + woff - v;
    off[t] = excl;
    if (t < nn) {
        rowptr2[node0 + t] = make_int2((int)gbase + excl, (int)gbase + excl + v);
        dinv[node0 + t] = rsqrtf(1.0f + (float)v);
    }
    __syncthreads();
    for (int i = t; i < count; i += 256) {
        unsigned en = entries[gbase + i];
        int loc = (int)(en & 255);
        int r = atomicAdd(&cur[loc], 1);
        csr[gbase + off[loc] + r] = (int)(en >> 8);
    }
}

// ---------------- weight conversions (single launch) ----------------

__global__ void cvt_w_k(const float* __restrict__ conv_w,
                        const float* __restrict__ lin1_w,
                        const float* __restrict__ lin2_w,
                        unsigned short* __restrict__ wt0,
                        unsigned short* __restrict__ wt1,
                        unsigned short* __restrict__ wt2) {
    int id = blockIdx.x * 256 + threadIdx.x;
    if (id < 16384) {
        int k = id >> 7, n = id & 127;
        wt0[n * 128 + k] = f2b(conv_w[k * 128 + n]);
    } else if (id < 16384 + 32768) {
        int i = id - 16384;
        wt1[i] = f2b(lin1_w[i]);
    } else if (id < 16384 + 32768 + 65536) {
        int i = id - 49152;
        wt2[i] = f2b(lin2_w[i]);
    }
}

// ---------------- MFMA bf16 GEMM for conv (fp32 A in-register cvt) ----------

__global__ __launch_bounds__(256) void mgemm0_k(
    const float* __restrict__ Af, const unsigned short* __restrict__ B,
    const float* __restrict__ dinv, unsigned short* __restrict__ Cout, int M)
{
    const int tid = threadIdx.x;
    const int wid = tid >> 6;
    const int lane = tid & 63;
    const int quad = lane >> 4;
    const int l16 = lane & 15;
    const int bm = blockIdx.x * 128 + (wid >> 1) * 64;
    const int bn = (wid & 1) * 64;

    const short8 zed = {0, 0, 0, 0, 0, 0, 0, 0};
    f32x4 acc[4][4];
#pragma unroll
    for (int i = 0; i < 4; ++i)
#pragma unroll
        for (int j = 0; j < 4; ++j) {
            f32x4 z = {0.f, 0.f, 0.f, 0.f};
            acc[i][j] = z;
        }

#pragma unroll
    for (int k0 = 0; k0 < 128; k0 += 32) {
        const int ka = k0 + quad * 8;
        short8 a[4], b[4];
#pragma unroll
        for (int t = 0; t < 4; ++t) {
            int m = bm + t * 16 + l16;
            short8 av = zed;
            if (m < M) {
                float4 f0 = *reinterpret_cast<const float4*>(Af + (size_t)m * 128 + ka);
                float4 f1 = *reinterpret_cast<const float4*>(Af + (size_t)m * 128 + ka + 4);
                av[0] = (short)f2b(f0.x); av[1] = (short)f2b(f0.y);
                av[2] = (short)f2b(f0.z); av[3] = (short)f2b(f0.w);
                av[4] = (short)f2b(f1.x); av[5] = (short)f2b(f1.y);
                av[6] = (short)f2b(f1.z); av[7] = (short)f2b(f1.w);
            }
            a[t] = av;
            int n = bn + t * 16 + l16;
            b[t] = *reinterpret_cast<const short8*>(B + (size_t)n * 128 + ka);
        }
#pragma unroll
        for (int i = 0; i < 4; ++i)
#pragma unroll
            for (int j = 0; j < 4; ++j)
                acc[i][j] = __builtin_amdgcn_mfma_f32_16x16x32_bf16(a[i], b[j], acc[i][j], 0, 0, 0);
    }

#pragma unroll
    for (int i = 0; i < 4; ++i)
#pragma unroll
        for (int r = 0; r < 4; ++r) {
            int row = bm + i * 16 + quad * 4 + r;
            if (row >= M) continue;
            float dv = dinv[row];
#pragma unroll
            for (int j = 0; j < 4; ++j) {
                int col = bn + j * 16 + l16;
                Cout[(size_t)row * 128 + col] = f2b(acc[i][j][r] * dv);
            }
        }
}

// ---------------- gather v4: 4 rows per wave-load, padded CSR ----------------

__global__ __launch_bounds__(256) void gather_k(
    const int2* __restrict__ rowptr2, const int* __restrict__ csr,
    const unsigned short* __restrict__ xws, const float* __restrict__ dinv,
    const float* __restrict__ x, const float* __restrict__ conv_b,
    unsigned short* __restrict__ h0)
{
    const int node = blockIdx.x * 4 + (threadIdx.x >> 6);
    if (node >= NNODES) return;
    const int lane = threadIdx.x & 63;
    const int sub = lane >> 4;
    const int c16 = lane & 15;

    const int2 se = rowptr2[node];
    const int start = se.x, end = se.y;

    float s[8];
    if (sub == 0) {
        short8 r = *reinterpret_cast<const short8*>(xws + (size_t)node * CIN + c16 * 8);
#pragma unroll
        for (int q = 0; q < 8; ++q) s[q] = b2f((unsigned short)r[q]);
    } else {
#pragma unroll
        for (int q = 0; q < 8; ++q) s[q] = 0.f;
    }

    for (int p = start; p < end; p += 16) {
        short8 r[4];
        int valid[4];
#pragma unroll
        for (int j = 0; j < 4; ++j) {
            int e = p + j * 4 + sub;
            bool a = e < end;
            int idx = a ? csr[e] : node;
            r[j] = *reinterpret_cast<const short8*>(xws + (size_t)idx * CIN + c16 * 8);
            valid[j] = a;
        }
#pragma unroll
        for (int j = 0; j < 4; ++j)
            if (valid[j]) {
#pragma unroll
                for (int q = 0; q < 8; ++q) s[q] += b2f((unsigned short)r[j][q]);
            }
    }

#pragma unroll
    for (int q = 0; q < 8; ++q) {
        s[q] += __shfl_xor(s[q], 16, 64);
        s[q] += __shfl_xor(s[q], 32, 64);
    }

    if (sub == 0) {
        float dvv = dinv[node];
        float4 b0 = *reinterpret_cast<const float4*>(conv_b + c16 * 8);
        float4 b1 = *reinterpret_cast<const float4*>(conv_b + c16 * 8 + 4);
        float4 x0 = *reinterpret_cast<const float4*>(x + (size_t)node * CIN + c16 * 8);
        float4 x1 = *reinterpret_cast<const float4*>(x + (size_t)node * CIN + c16 * 8 + 4);
        float o[8];
        o[0] = fmaxf(s[0] * dvv + b0.x, 0.f) + x0.x;
        o[1] = fmaxf(s[1] * dvv + b0.y, 0.f) + x0.y;
        o[2] = fmaxf(s[2] * dvv + b0.z, 0.f) + x0.z;
        o[3] = fmaxf(s[3] * dvv + b0.w, 0.f) + x0.w;
        o[4] = fmaxf(s[4] * dvv + b1.x, 0.f) + x1.x;
        o[5] = fmaxf(s[5] * dvv + b1.y, 0.f) + x1.y;
        o[6] = fmaxf(s[6] * dvv + b1.z, 0.f) + x1.z;
        o[7] = fmaxf(s[7] * dvv + b1.w, 0.f) + x1.w;
        short8 pk;
#pragma unroll
        for (int q = 0; q < 8; ++q) pk[q] = (short)f2b(o[q]);
        *reinterpret_cast<short8*>(h0 + (size_t)node * CIN + c16 * 8) = pk;
    }
}

// ---------------- out init (harness poisons d_out every call) ----------------

__global__ void init_out_k(float* __restrict__ out, const float* __restrict__ b3) {
    int i = blockIdx.x * 256 + threadIdx.x;
    if (i < NGRAPH) out[i] = b3[0];
}

// ---------------- m97-style staged GEMM ----------------
// 128x128 tile/block, 256 thr (4 waves, 64x64 each), BK=32, single-buffered
// 2-barrier K-loop, A+B staged via global_load_lds (16B/lane DMA).
// LDS layout: [row][chunk] where chunk = 16B (8 bf16 of k); the k-chunk each
// lane FETCHES is XOR-permuted (qg = (s&3)^(row&3)) so that ds_read_b128 of
// fragment (row=l16-varying, chunk=quad^(row&3)) lands 2 lanes/bank (free).
// MODE 1: C = relu(A@B^T + bias) -> bf16 h1
// MODE 2: fused final: out[row/20] += sum_col relu(v + bias[col]) * w3[col]

template <int LDK, int KT, int MODE>
__global__ __launch_bounds__(256) void sgemm_k(
    const unsigned short* __restrict__ A, const unsigned short* __restrict__ B,
    const float* __restrict__ bias, const float* __restrict__ w3,
    unsigned short* __restrict__ Cout, float* __restrict__ out, int M)
{
    __shared__ unsigned short As[128 * 32];   // 8 KB
    __shared__ unsigned short Bs[128 * 32];   // 8 KB
    const int tid = threadIdx.x;
    const int wave = tid >> 6;
    const int lane = tid & 63;
    const int quad = lane >> 4;
    const int l16 = lane & 15;
    const int rh = (wave >> 1) * 64;     // row half of this wave
    const int ch = (wave & 1) * 64;      // col half
    const int bm = blockIdx.x * 128;
    const int bn = blockIdx.y * 128;

    f32x4 acc[4][4];
#pragma unroll
    for (int i = 0; i < 4; ++i)
#pragma unroll
        for (int j = 0; j < 4; ++j) {
            f32x4 z = {0.f, 0.f, 0.f, 0.f};
            acc[i][j] = z;
        }

    // per-thread staging slots: s = c*256 + tid, row = s>>2, fetched chunk
    // qg = (s&3) ^ (row&3). OOB rows read adjacent workspace (guarded at write).
    const int s0 = tid, s1 = 256 + tid;
    const int r0 = s0 >> 2, q0 = (s0 & 3) ^ (r0 & 3);
    const int r1 = s1 >> 2, q1 = (s1 & 3) ^ (r1 & 3);
    const size_t ldsoff0 = (size_t)(wave * 64) * 16 + (lane & 63) * 16;
    const size_t ldsoff1 = (size_t)(256 + wave * 64) * 16 + (lane & 63) * 16;

    for (int kt = 0; kt < KT; ++kt) {
        const int k0 = kt * 32;
        gld16(A + (size_t)(bm + r0) * LDK + k0 + q0 * 8, (char*)As + ldsoff0);
        gld16(A + (size_t)(bm + r1) * LDK + k0 + q1 * 8, (char*)As + ldsoff1);
        gld16(B + (size_t)(bn + r0) * LDK + k0 + q0 * 8, (char*)Bs + ldsoff0);
        gld16(B + (size_t)(bn + r1) * LDK + k0 + q1 * 8, (char*)Bs + ldsoff1);
        __syncthreads();   // compiler drains vmcnt before s_barrier

        short8 a[4], b[4];
#pragma unroll
        for (int t = 0; t < 4; ++t) {
            int R = rh + t * 16 + l16;
            a[t] = *reinterpret_cast<const short8*>(
                (const char*)As + R * 64 + ((quad ^ (R & 3)) << 4));
            int Cn = ch + t * 16 + l16;
            b[t] = *reinterpret_cast<const short8*>(
                (const char*)Bs + Cn * 64 + ((quad ^ (Cn & 3)) << 4));
        }
#pragma unroll
        for (int i = 0; i < 4; ++i)
#pragma unroll
            for (int j = 0; j < 4; ++j)
                acc[i][j] = __builtin_amdgcn_mfma_f32_16x16x32_bf16(a[i], b[j], acc[i][j], 0, 0, 0);
        __syncthreads();
    }

    if (MODE == 1) {
#pragma unroll
        for (int nt = 0; nt < 4; ++nt) {
            int col = bn + ch + nt * 16 + l16;
            float bv = bias[col];
#pragma unroll
            for (int mt = 0; mt < 4; ++mt)
#pragma unroll
                for (int r = 0; r < 4; ++r) {
                    int row = bm + rh + mt * 16 + quad * 4 + r;
                    if (row < M)
                        Cout[(size_t)row * 256 + col] = f2b(fmaxf(acc[mt][nt][r] + bv, 0.f));
                }
        }
    } else {
        float part[4][4];
#pragma unroll
        for (int mt = 0; mt < 4; ++mt)
#pragma unroll
            for (int r = 0; r < 4; ++r) part[mt][r] = 0.f;
#pragma unroll
        for (int nt = 0; nt < 4; ++nt) {
            int col = bn + ch + nt * 16 + l16;
            float bs = bias[col];
            float wv3 = w3[col];
#pragma unroll
            for (int mt = 0; mt < 4; ++mt)
#pragma unroll
                for (int r = 0; r < 4; ++r)
                    part[mt][r] += fmaxf(acc[mt][nt][r] + bs, 0.f) * wv3;
        }
#pragma unroll
        for (int mt = 0; mt < 4; ++mt)
#pragma unroll
            for (int r = 0; r < 4; ++r) {
                float v = part[mt][r];
                v += __shfl_xor(v, 1, 64);
                v += __shfl_xor(v, 2, 64);
                v += __shfl_xor(v, 4, 64);
                v += __shfl_xor(v, 8, 64);
                part[mt][r] = v;
            }
        if (l16 == 0) {
#pragma unroll
            for (int mt = 0; mt < 4; ++mt)
#pragma unroll
                for (int r = 0; r < 4; ++r) {
                    int row = bm + rh + mt * 16 + quad * 4 + r;
                    if (row < M) atomicAdd(&out[row / ACT], part[mt][r]);
                }
        }
    }
}

// ---------------- launch ----------------

extern "C" void kernel_launch(void* const* d_in, const int* in_sizes, int n_in,
                              void* d_out, int out_size, void* d_ws, size_t ws_size,
                              hipStream_t stream)
{
    const float* x      = (const float*)d_in[0];
    const int*   ei     = (const int*)  d_in[1];
    const float* conv_w = (const float*)d_in[2];
    const float* conv_b = (const float*)d_in[3];
    const float* lin1_w = (const float*)d_in[4];
    const float* lin1_b = (const float*)d_in[5];
    const float* lin2_w = (const float*)d_in[6];
    const float* lin2_b = (const float*)d_in[7];
    const float* lin3_w = (const float*)d_in[8];
    const float* lin3_b = (const float*)d_in[9];
    float* out = (float*)d_out;

    // Workspace (~130 MB):
    //   h1 bf16 [N*256] 51.2 MB | xws bf16 [N*128] 25.6 MB | h0 bf16 25.6 MB
    //   entries u32 [NB*CAP] 12.8 MB | csr 12.8 MB | rowptr2 | dinv | bfill | wts
    unsigned short* h1      = (unsigned short*)d_ws;
    unsigned short* xws     = h1 + (size_t)25600000;
    unsigned short* h0      = xws + (size_t)12800000;
    unsigned*       entries = (unsigned*)(h0 + (size_t)12800000);
    int*            csr     = (int*)(entries + (size_t)NB * CAP);
    int2*           rowptr2 = (int2*)(csr + (size_t)NB * CAP);
    float*          dinv    = (float*)(rowptr2 + NNODES);
    int*            bfill   = (int*)(dinv + NNODES);
    unsigned short* wt0     = (unsigned short*)(bfill + NB + 8);
    unsigned short* wt1     = wt0 + 16384;
    unsigned short* wt2     = wt1 + 32768;

    // CSR build (fixed-capacity bucket windows)
    hipMemsetAsync(bfill, 0, NB * sizeof(int), stream);
    bin_k<<<BIN_WGS, 256, 0, stream>>>(ei, bfill, entries);
    bucket_build_k<<<NB, 256, 0, stream>>>(entries, bfill, rowptr2, csr, dinv);

    // weight conversions (one launch)
    cvt_w_k<<<(114688 + 255) / 256, 256, 0, stream>>>(conv_w, lin1_w, lin2_w, wt0, wt1, wt2);

    // gemm0: xws = (x @ conv_w) * dinv[row]
    mgemm0_k<<<(NNODES + 127) / 128, 256, 0, stream>>>(x, wt0, dinv, xws, NNODES);

    // gather + conv epilogue -> h0 bf16
    gather_k<<<(NNODES + 3) / 4, 256, 0, stream>>>(rowptr2, csr, xws, dinv, x, conv_b, h0);

    // out = b3, then fused gemm2 accumulates into it
    init_out_k<<<(NGRAPH + 255) / 256, 256, 0, stream>>>(out, lin3_b);

    const int gm = (NNODES + 127) / 128;   // 782

    // gemm1: h1 = relu(h0 @ W1^T + b1)   (m97-style staged)
    sgemm_k<128, 4, 1><<<dim3(gm, 2), 256, 0, stream>>>(h0, wt1, lin1_b, nullptr, h1, nullptr, NNODES);

    // gemm2 + fused final: out += rowsum(relu(h1 @ W2^T + b2)) . w3
    sgemm_k<256, 8, 2><<<dim3(gm, 2), 256, 0, stream>>>(h1, wt2, lin2_b, lin3_w, nullptr, out, NNODES);
}

// Round 10
// 366.927 us; speedup vs baseline: 1.0933x; 1.0289x over previous
//
#include <hip/hip_runtime.h>
#include <hip/hip_bf16.h>
#include <cstddef>

#define NNODES 100000
#define NEDGES 1600000
#define CIN 128
#define HID 256
#define ACT 20
#define NGRAPH (NNODES / ACT)
#define BSHIFT 8
#define NB ((NNODES + 255) >> 8)     // 391 buckets of 256 nodes
#define BIN_WGS 512
#define CAP 8192                     // bucket window capacity (mean fill 4096)

typedef __attribute__((ext_vector_type(8))) short short8;
typedef __attribute__((ext_vector_type(4))) float f32x4;

__device__ __forceinline__ unsigned short f2b(float f) {
    unsigned u = __float_as_uint(f);
    u += 0x7FFF + ((u >> 16) & 1);          // round-to-nearest-even
    return (unsigned short)(u >> 16);
}
__device__ __forceinline__ float b2f(unsigned short h) {
    return __uint_as_float(((unsigned)h) << 16);
}

// ---------------- bucketed CSR build (fixed-capacity windows) ----------------

__global__ __launch_bounds__(256) void bin_k(const int* __restrict__ ei,
                                             int* __restrict__ bfill,
                                             unsigned* __restrict__ entries) {
    __shared__ int cnt[NB], base[NB], cur[NB];
    for (int i = threadIdx.x; i < NB; i += 256) { cnt[i] = 0; cur[i] = 0; }
    __syncthreads();
    const int per = NEDGES / BIN_WGS;      // 3125
    const int s = blockIdx.x * per;
    const int e = s + per;
    for (int i = s + threadIdx.x; i < e; i += 256)
        atomicAdd(&cnt[ei[NEDGES + i] >> BSHIFT], 1);
    __syncthreads();
    for (int i = threadIdx.x; i < NB; i += 256)
        base[i] = cnt[i] ? atomicAdd(&bfill[i], cnt[i]) : 0;
    __syncthreads();
    for (int i = s + threadIdx.x; i < e; i += 256) {
        int src = ei[i], dst = ei[NEDGES + i];
        int b = dst >> BSHIFT;
        int r = base[b] + atomicAdd(&cur[b], 1);
        if (r < CAP)
            entries[(size_t)b * CAP + r] = ((unsigned)src << 8) | (unsigned)(dst & 255);
    }
}

__global__ __launch_bounds__(256) void bucket_build_k(
    const unsigned* __restrict__ entries, const int* __restrict__ bfill,
    int2* __restrict__ rowptr2, int* __restrict__ csr, float* __restrict__ dinv) {
    const int b = blockIdx.x;
    const int count = min(bfill[b], CAP);
    const int node0 = b << BSHIFT;
    const int nn = min(256, NNODES - node0);
    const size_t gbase = (size_t)b * CAP;
    __shared__ int cnt[256], off[256], cur[256];
    const int t = threadIdx.x;
    cnt[t] = 0; cur[t] = 0;
    __syncthreads();
    for (int i = t; i < count; i += 256)
        atomicAdd(&cnt[entries[gbase + i] & 255], 1);
    __syncthreads();
    int lane = t & 63, wid = t >> 6;
    int v = cnt[t];
    int inc = v;
#pragma unroll
    for (int o = 1; o < 64; o <<= 1) {
        int tv = __shfl_up(inc, o, 64);
        if (lane >= o) inc += tv;
    }
    __shared__ int wsum[4];
    if (lane == 63) wsum[wid] = inc;
    __syncthreads();
    int woff = 0;
#pragma unroll
    for (int w = 0; w < 4; ++w) woff += (w < wid) ? wsum[w] : 0;
    int excl = inc + woff - v;
    off[t] = excl;
    if (t < nn) {
        rowptr2[node0 + t] = make_int2((int)gbase + excl, (int)gbase + excl + v);
        dinv[node0 + t] = rsqrtf(1.0f + (float)v);
    }
    __syncthreads();
    for (int i = t; i < count; i += 256) {
        unsigned en = entries[gbase + i];
        int loc = (int)(en & 255);
        int r = atomicAdd(&cur[loc], 1);
        csr[gbase + off[loc] + r] = (int)(en >> 8);
    }
}

// ---------------- weight conversions (single launch) ----------------

__global__ void cvt_w_k(const float* __restrict__ conv_w,
                        const float* __restrict__ lin1_w,
                        const float* __restrict__ lin2_w,
                        unsigned short* __restrict__ wt0,
                        unsigned short* __restrict__ wt1,
                        unsigned short* __restrict__ wt2) {
    int id = blockIdx.x * 256 + threadIdx.x;
    if (id < 16384) {
        int k = id >> 7, n = id & 127;
        wt0[n * 128 + k] = f2b(conv_w[k * 128 + n]);
    } else if (id < 16384 + 32768) {
        int i = id - 16384;
        wt1[i] = f2b(lin1_w[i]);
    } else if (id < 16384 + 32768 + 65536) {
        int i = id - 49152;
        wt2[i] = f2b(lin2_w[i]);
    }
}

// ---------------- MFMA bf16 GEMM for conv (fp32 A, reg-pipelined) ----------

__global__ __launch_bounds__(256) void mgemm0_k(
    const float* __restrict__ Af, const unsigned short* __restrict__ B,
    const float* __restrict__ dinv, unsigned short* __restrict__ Cout, int M)
{
    const int tid = threadIdx.x;
    const int wid = tid >> 6;
    const int lane = tid & 63;
    const int quad = lane >> 4;
    const int l16 = lane & 15;
    const int bm = blockIdx.x * 128 + (wid >> 1) * 64;
    const int bn = (wid & 1) * 64;

    const float* pa[4];
    const unsigned short* pb[4];
#pragma unroll
    for (int t = 0; t < 4; ++t) {
        int m = bm + t * 16 + l16; if (m >= M) m = M - 1;   // clamp; store guarded
        pa[t] = Af + (size_t)m * 128 + quad * 8;
        int n = bn + t * 16 + l16;
        pb[t] = B + (size_t)n * 128 + quad * 8;
    }

    f32x4 acc[4][4];
#pragma unroll
    for (int i = 0; i < 4; ++i)
#pragma unroll
        for (int j = 0; j < 4; ++j) {
            f32x4 z = {0.f, 0.f, 0.f, 0.f};
            acc[i][j] = z;
        }

    float4 afl[2][4][2];
    short8 bf[2][4];
#pragma unroll
    for (int t = 0; t < 4; ++t) {
        afl[0][t][0] = *reinterpret_cast<const float4*>(pa[t]);
        afl[0][t][1] = *reinterpret_cast<const float4*>(pa[t] + 4);
        bf[0][t] = *reinterpret_cast<const short8*>(pb[t]);
    }

#pragma unroll
    for (int kt = 0; kt < 4; ++kt) {
        const int cur = kt & 1, nxt = cur ^ 1;
        if (kt < 3) {
#pragma unroll
            for (int t = 0; t < 4; ++t) {
                afl[nxt][t][0] = *reinterpret_cast<const float4*>(pa[t] + (kt + 1) * 32);
                afl[nxt][t][1] = *reinterpret_cast<const float4*>(pa[t] + (kt + 1) * 32 + 4);
                bf[nxt][t] = *reinterpret_cast<const short8*>(pb[t] + (kt + 1) * 32);
            }
        }
        short8 a[4];
#pragma unroll
        for (int t = 0; t < 4; ++t) {
            float4 f0 = afl[cur][t][0], f1 = afl[cur][t][1];
            short8 av;
            av[0] = (short)f2b(f0.x); av[1] = (short)f2b(f0.y);
            av[2] = (short)f2b(f0.z); av[3] = (short)f2b(f0.w);
            av[4] = (short)f2b(f1.x); av[5] = (short)f2b(f1.y);
            av[6] = (short)f2b(f1.z); av[7] = (short)f2b(f1.w);
            a[t] = av;
        }
#pragma unroll
        for (int i = 0; i < 4; ++i)
#pragma unroll
            for (int j = 0; j < 4; ++j)
                acc[i][j] = __builtin_amdgcn_mfma_f32_16x16x32_bf16(a[i], bf[cur][j], acc[i][j], 0, 0, 0);
    }

#pragma unroll
    for (int i = 0; i < 4; ++i)
#pragma unroll
        for (int r = 0; r < 4; ++r) {
            int row = bm + i * 16 + quad * 4 + r;
            if (row >= M) continue;
            float dv = dinv[row];
#pragma unroll
            for (int j = 0; j < 4; ++j) {
                int col = bn + j * 16 + l16;
                Cout[(size_t)row * 128 + col] = f2b(acc[i][j][r] * dv);
            }
        }
}

// ---------------- gather v4: 4 rows per wave-load, padded CSR ----------------

__global__ __launch_bounds__(256) void gather_k(
    const int2* __restrict__ rowptr2, const int* __restrict__ csr,
    const unsigned short* __restrict__ xws, const float* __restrict__ dinv,
    const float* __restrict__ x, const float* __restrict__ conv_b,
    unsigned short* __restrict__ h0)
{
    const int node = blockIdx.x * 4 + (threadIdx.x >> 6);
    if (node >= NNODES) return;
    const int lane = threadIdx.x & 63;
    const int sub = lane >> 4;
    const int c16 = lane & 15;

    const int2 se = rowptr2[node];
    const int start = se.x, end = se.y;

    float s[8];
    if (sub == 0) {
        short8 r = *reinterpret_cast<const short8*>(xws + (size_t)node * CIN + c16 * 8);
#pragma unroll
        for (int q = 0; q < 8; ++q) s[q] = b2f((unsigned short)r[q]);
    } else {
#pragma unroll
        for (int q = 0; q < 8; ++q) s[q] = 0.f;
    }

    for (int p = start; p < end; p += 16) {
        short8 r[4];
        int valid[4];
#pragma unroll
        for (int j = 0; j < 4; ++j) {
            int e = p + j * 4 + sub;
            bool a = e < end;
            int idx = a ? csr[e] : node;
            r[j] = *reinterpret_cast<const short8*>(xws + (size_t)idx * CIN + c16 * 8);
            valid[j] = a;
        }
#pragma unroll
        for (int j = 0; j < 4; ++j)
            if (valid[j]) {
#pragma unroll
                for (int q = 0; q < 8; ++q) s[q] += b2f((unsigned short)r[j][q]);
            }
    }

#pragma unroll
    for (int q = 0; q < 8; ++q) {
        s[q] += __shfl_xor(s[q], 16, 64);
        s[q] += __shfl_xor(s[q], 32, 64);
    }

    if (sub == 0) {
        float dvv = dinv[node];
        float4 b0 = *reinterpret_cast<const float4*>(conv_b + c16 * 8);
        float4 b1 = *reinterpret_cast<const float4*>(conv_b + c16 * 8 + 4);
        float4 x0 = *reinterpret_cast<const float4*>(x + (size_t)node * CIN + c16 * 8);
        float4 x1 = *reinterpret_cast<const float4*>(x + (size_t)node * CIN + c16 * 8 + 4);
        float o[8];
        o[0] = fmaxf(s[0] * dvv + b0.x, 0.f) + x0.x;
        o[1] = fmaxf(s[1] * dvv + b0.y, 0.f) + x0.y;
        o[2] = fmaxf(s[2] * dvv + b0.z, 0.f) + x0.z;
        o[3] = fmaxf(s[3] * dvv + b0.w, 0.f) + x0.w;
        o[4] = fmaxf(s[4] * dvv + b1.x, 0.f) + x1.x;
        o[5] = fmaxf(s[5] * dvv + b1.y, 0.f) + x1.y;
        o[6] = fmaxf(s[6] * dvv + b1.z, 0.f) + x1.z;
        o[7] = fmaxf(s[7] * dvv + b1.w, 0.f) + x1.w;
        short8 pk;
#pragma unroll
        for (int q = 0; q < 8; ++q) pk[q] = (short)f2b(o[q]);
        *reinterpret_cast<short8*>(h0 + (size_t)node * CIN + c16 * 8) = pk;
    }
}

// ---------------- register-pipelined GEMM (no LDS, no barriers) ----------
// 128x128 tile/block, 4 waves (64x64 each); frags for kt+1 prefetched into
// registers while MFMAs consume kt.
// MODE 1: C = relu(A@B^T + bias) -> bf16 Cout (stride 256)
// MODE 2: rowsum[row*4 + blockIdx.y*2 + (wave&1)] = partial w3-dot over this
//         wave's 64 cols.  4 slots/row, single writer each (waves 0,1 share
//         rows but differ in ch -> separate slots; round-9 race fixed).

template <int LDK, int KT, int MODE>
__global__ __launch_bounds__(256) void rgemm_k(
    const unsigned short* __restrict__ A, const unsigned short* __restrict__ B,
    const float* __restrict__ bias, const float* __restrict__ w3,
    unsigned short* __restrict__ Cout, float* __restrict__ rowsum, int M)
{
    const int tid = threadIdx.x;
    const int wave = tid >> 6;
    const int lane = tid & 63;
    const int quad = lane >> 4;
    const int l16 = lane & 15;
    const int rh = (wave >> 1) * 64;
    const int ch = (wave & 1) * 64;
    const int bm = blockIdx.x * 128;
    const int bn = blockIdx.y * 128;

    const unsigned short* pa[4];
    const unsigned short* pb[4];
#pragma unroll
    for (int t = 0; t < 4; ++t) {
        int m = bm + rh + t * 16 + l16; if (m >= M) m = M - 1;   // clamp; guarded at store
        pa[t] = A + (size_t)m * LDK + quad * 8;
        int n = bn + ch + t * 16 + l16;
        pb[t] = B + (size_t)n * LDK + quad * 8;
    }

    f32x4 acc[4][4];
#pragma unroll
    for (int i = 0; i < 4; ++i)
#pragma unroll
        for (int j = 0; j < 4; ++j) {
            f32x4 z = {0.f, 0.f, 0.f, 0.f};
            acc[i][j] = z;
        }

    short8 af[2][4], bf[2][4];
#pragma unroll
    for (int t = 0; t < 4; ++t) {
        af[0][t] = *reinterpret_cast<const short8*>(pa[t]);
        bf[0][t] = *reinterpret_cast<const short8*>(pb[t]);
    }

#pragma unroll
    for (int kt = 0; kt < KT; ++kt) {
        const int cur = kt & 1, nxt = cur ^ 1;
        if (kt + 1 < KT) {
#pragma unroll
            for (int t = 0; t < 4; ++t) {
                af[nxt][t] = *reinterpret_cast<const short8*>(pa[t] + (kt + 1) * 32);
                bf[nxt][t] = *reinterpret_cast<const short8*>(pb[t] + (kt + 1) * 32);
            }
        }
#pragma unroll
        for (int i = 0; i < 4; ++i)
#pragma unroll
            for (int j = 0; j < 4; ++j)
                acc[i][j] = __builtin_amdgcn_mfma_f32_16x16x32_bf16(af[cur][i], bf[cur][j], acc[i][j], 0, 0, 0);
    }

    if (MODE == 1) {
#pragma unroll
        for (int nt = 0; nt < 4; ++nt) {
            int col = bn + ch + nt * 16 + l16;
            float bv = bias[col];
#pragma unroll
            for (int mt = 0; mt < 4; ++mt)
#pragma unroll
                for (int r = 0; r < 4; ++r) {
                    int row = bm + rh + mt * 16 + quad * 4 + r;
                    if (row < M)
                        Cout[(size_t)row * 256 + col] = f2b(fmaxf(acc[mt][nt][r] + bv, 0.f));
                }
        }
    } else {
        float part[4][4];
#pragma unroll
        for (int mt = 0; mt < 4; ++mt)
#pragma unroll
            for (int r = 0; r < 4; ++r) part[mt][r] = 0.f;
#pragma unroll
        for (int nt = 0; nt < 4; ++nt) {
            int col = bn + ch + nt * 16 + l16;
            float bs = bias[col];
            float wv3 = w3[col];
#pragma unroll
            for (int mt = 0; mt < 4; ++mt)
#pragma unroll
                for (int r = 0; r < 4; ++r)
                    part[mt][r] += fmaxf(acc[mt][nt][r] + bs, 0.f) * wv3;
        }
#pragma unroll
        for (int mt = 0; mt < 4; ++mt)
#pragma unroll
            for (int r = 0; r < 4; ++r) {
                float v = part[mt][r];
                v += __shfl_xor(v, 1, 64);
                v += __shfl_xor(v, 2, 64);
                v += __shfl_xor(v, 4, 64);
                v += __shfl_xor(v, 8, 64);
                part[mt][r] = v;
            }
        if (l16 == 0) {
            const int slot = blockIdx.y * 2 + (wave & 1);
#pragma unroll
            for (int mt = 0; mt < 4; ++mt)
#pragma unroll
                for (int r = 0; r < 4; ++r) {
                    int row = bm + rh + mt * 16 + quad * 4 + r;
                    if (row < M) rowsum[(size_t)row * 4 + slot] = part[mt][r];
                }
        }
    }
}

// ---------------- final: out[g] = b3 + sum of 80 rowsum slots ----------------

__global__ __launch_bounds__(256) void final_k(
    const float* __restrict__ rowsum, const float* __restrict__ b3,
    float* __restrict__ out)
{
    int g = blockIdx.x * 256 + threadIdx.x;
    if (g >= NGRAPH) return;
    const float4* p = reinterpret_cast<const float4*>(rowsum + (size_t)g * 80);
    float s = 0.f;
#pragma unroll
    for (int i = 0; i < 20; ++i) {
        float4 v = p[i];
        s += (v.x + v.y) + (v.z + v.w);
    }
    out[g] = s + b3[0];
}

// ---------------- launch ----------------

extern "C" void kernel_launch(void* const* d_in, const int* in_sizes, int n_in,
                              void* d_out, int out_size, void* d_ws, size_t ws_size,
                              hipStream_t stream)
{
    const float* x      = (const float*)d_in[0];
    const int*   ei     = (const int*)  d_in[1];
    const float* conv_w = (const float*)d_in[2];
    const float* conv_b = (const float*)d_in[3];
    const float* lin1_w = (const float*)d_in[4];
    const float* lin1_b = (const float*)d_in[5];
    const float* lin2_w = (const float*)d_in[6];
    const float* lin2_b = (const float*)d_in[7];
    const float* lin3_w = (const float*)d_in[8];
    const float* lin3_b = (const float*)d_in[9];
    float* out = (float*)d_out;

    // Workspace (~132 MB):
    //   h1 bf16 [N*256] | xws bf16 [N*128] | h0 bf16 [N*128]
    //   entries u32 [NB*CAP] | csr [NB*CAP] | rowptr2 | dinv | bfill
    //   wt0/wt1/wt2 | rowsum fp32 [100096*4]
    unsigned short* h1      = (unsigned short*)d_ws;
    unsigned short* xws     = h1 + (size_t)25600000;
    unsigned short* h0      = xws + (size_t)12800000;
    unsigned*       entries = (unsigned*)(h0 + (size_t)12800000);
    int*            csr     = (int*)(entries + (size_t)NB * CAP);
    int2*           rowptr2 = (int2*)(csr + (size_t)NB * CAP);
    float*          dinv    = (float*)(rowptr2 + NNODES);
    int*            bfill   = (int*)(dinv + NNODES);
    unsigned short* wt0     = (unsigned short*)(bfill + NB + 8);
    unsigned short* wt1     = wt0 + 16384;
    unsigned short* wt2     = wt1 + 32768;
    float*          rowsum  = (float*)(wt2 + 65536);

    // CSR build (fixed-capacity bucket windows)
    hipMemsetAsync(bfill, 0, NB * sizeof(int), stream);
    bin_k<<<BIN_WGS, 256, 0, stream>>>(ei, bfill, entries);
    bucket_build_k<<<NB, 256, 0, stream>>>(entries, bfill, rowptr2, csr, dinv);

    // weight conversions (one launch)
    cvt_w_k<<<(114688 + 255) / 256, 256, 0, stream>>>(conv_w, lin1_w, lin2_w, wt0, wt1, wt2);

    // gemm0: xws = (x @ conv_w) * dinv[row]
    mgemm0_k<<<(NNODES + 127) / 128, 256, 0, stream>>>(x, wt0, dinv, xws, NNODES);

    // gather + conv epilogue -> h0 bf16
    gather_k<<<(NNODES + 3) / 4, 256, 0, stream>>>(rowptr2, csr, xws, dinv, x, conv_b, h0);

    const int gm = (NNODES + 127) / 128;   // 782

    // gemm1: h1 = relu(h0 @ W1^T + b1)   (register-pipelined)
    rgemm_k<128, 4, 1><<<dim3(gm, 2), 256, 0, stream>>>(h0, wt1, lin1_b, nullptr, h1, nullptr, NNODES);

    // gemm2 + fused w3-dot -> rowsum (4 slots/row, no atomics, no races)
    rgemm_k<256, 8, 2><<<dim3(gm, 2), 256, 0, stream>>>(h1, wt2, lin2_b, lin3_w, nullptr, rowsum, NNODES);

    // out[g] = b3 + sum of this graph's 80 rowsum slots
    final_k<<<(NGRAPH + 255) / 256, 256, 0, stream>>>(rowsum, lin3_b, out);
}

// Round 11
// 363.617 us; speedup vs baseline: 1.1033x; 1.0091x over previous
//
#include <hip/hip_runtime.h>
#include <hip/hip_bf16.h>
#include <cstddef>

#define NNODES 100000
#define NEDGES 1600000
#define CIN 128
#define HID 256
#define ACT 20
#define NGRAPH (NNODES / ACT)
#define BSHIFT 8
#define NB ((NNODES + 255) >> 8)     // 391 buckets of 256 nodes
#define BIN_WGS 512
#define CAP 8192                     // bucket window capacity (mean fill 4096)

typedef __attribute__((ext_vector_type(8))) short short8;
typedef __attribute__((ext_vector_type(4))) float f32x4;

__device__ __forceinline__ unsigned short f2b(float f) {
    unsigned u = __float_as_uint(f);
    u += 0x7FFF + ((u >> 16) & 1);          // round-to-nearest-even
    return (unsigned short)(u >> 16);
}
__device__ __forceinline__ float b2f(unsigned short h) {
    return __uint_as_float(((unsigned)h) << 16);
}

// ---------------- bucketed CSR build (fixed-capacity windows) ----------------

__global__ __launch_bounds__(256) void bin_k(const int* __restrict__ ei,
                                             int* __restrict__ bfill,
                                             unsigned* __restrict__ entries) {
    __shared__ int cnt[NB], base[NB], cur[NB];
    for (int i = threadIdx.x; i < NB; i += 256) { cnt[i] = 0; cur[i] = 0; }
    __syncthreads();
    const int per = NEDGES / BIN_WGS;      // 3125
    const int s = blockIdx.x * per;
    const int e = s + per;
    for (int i = s + threadIdx.x; i < e; i += 256)
        atomicAdd(&cnt[ei[NEDGES + i] >> BSHIFT], 1);
    __syncthreads();
    for (int i = threadIdx.x; i < NB; i += 256)
        base[i] = cnt[i] ? atomicAdd(&bfill[i], cnt[i]) : 0;
    __syncthreads();
    for (int i = s + threadIdx.x; i < e; i += 256) {
        int src = ei[i], dst = ei[NEDGES + i];
        int b = dst >> BSHIFT;
        int r = base[b] + atomicAdd(&cur[b], 1);
        if (r < CAP)
            entries[(size_t)b * CAP + r] = ((unsigned)src << 8) | (unsigned)(dst & 255);
    }
}

__global__ __launch_bounds__(256) void bucket_build_k(
    const unsigned* __restrict__ entries, const int* __restrict__ bfill,
    int2* __restrict__ rowptr2, int* __restrict__ csr, float* __restrict__ dinv) {
    const int b = blockIdx.x;
    const int count = min(bfill[b], CAP);
    const int node0 = b << BSHIFT;
    const int nn = min(256, NNODES - node0);
    const size_t gbase = (size_t)b * CAP;
    __shared__ int cnt[256], off[256], cur[256];
    const int t = threadIdx.x;
    cnt[t] = 0; cur[t] = 0;
    __syncthreads();
    for (int i = t; i < count; i += 256)
        atomicAdd(&cnt[entries[gbase + i] & 255], 1);
    __syncthreads();
    int lane = t & 63, wid = t >> 6;
    int v = cnt[t];
    int inc = v;
#pragma unroll
    for (int o = 1; o < 64; o <<= 1) {
        int tv = __shfl_up(inc, o, 64);
        if (lane >= o) inc += tv;
    }
    __shared__ int wsum[4];
    if (lane == 63) wsum[wid] = inc;
    __syncthreads();
    int woff = 0;
#pragma unroll
    for (int w = 0; w < 4; ++w) woff += (w < wid) ? wsum[w] : 0;
    int excl = inc + woff - v;
    off[t] = excl;
    if (t < nn) {
        rowptr2[node0 + t] = make_int2((int)gbase + excl, (int)gbase + excl + v);
        dinv[node0 + t] = rsqrtf(1.0f + (float)v);
    }
    __syncthreads();
    for (int i = t; i < count; i += 256) {
        unsigned en = entries[gbase + i];
        int loc = (int)(en & 255);
        int r = atomicAdd(&cur[loc], 1);
        csr[gbase + off[loc] + r] = (int)(en >> 8);
    }
}

// ---------------- weight conversions (single launch) ----------------

__global__ void cvt_w_k(const float* __restrict__ conv_w,
                        const float* __restrict__ lin1_w,
                        const float* __restrict__ lin2_w,
                        unsigned short* __restrict__ wt0,
                        unsigned short* __restrict__ wt1,
                        unsigned short* __restrict__ wt2) {
    int id = blockIdx.x * 256 + threadIdx.x;
    if (id < 16384) {
        int k = id >> 7, n = id & 127;
        wt0[n * 128 + k] = f2b(conv_w[k * 128 + n]);
    } else if (id < 16384 + 32768) {
        int i = id - 16384;
        wt1[i] = f2b(lin1_w[i]);
    } else if (id < 16384 + 32768 + 65536) {
        int i = id - 49152;
        wt2[i] = f2b(lin2_w[i]);
    }
}

// ---------------- MFMA bf16 GEMM for conv (fp32 A, reg-pipelined) ----------

__global__ __launch_bounds__(256) void mgemm0_k(
    const float* __restrict__ Af, const unsigned short* __restrict__ B,
    const float* __restrict__ dinv, unsigned short* __restrict__ Cout, int M)
{
    const int tid = threadIdx.x;
    const int wid = tid >> 6;
    const int lane = tid & 63;
    const int quad = lane >> 4;
    const int l16 = lane & 15;
    const int bm = blockIdx.x * 128 + (wid >> 1) * 64;
    const int bn = (wid & 1) * 64;

    const float* pa[4];
    const unsigned short* pb[4];
#pragma unroll
    for (int t = 0; t < 4; ++t) {
        int m = bm + t * 16 + l16; if (m >= M) m = M - 1;   // clamp; store guarded
        pa[t] = Af + (size_t)m * 128 + quad * 8;
        int n = bn + t * 16 + l16;
        pb[t] = B + (size_t)n * 128 + quad * 8;
    }

    f32x4 acc[4][4];
#pragma unroll
    for (int i = 0; i < 4; ++i)
#pragma unroll
        for (int j = 0; j < 4; ++j) {
            f32x4 z = {0.f, 0.f, 0.f, 0.f};
            acc[i][j] = z;
        }

    float4 afl[2][4][2];
    short8 bf[2][4];
#pragma unroll
    for (int t = 0; t < 4; ++t) {
        afl[0][t][0] = *reinterpret_cast<const float4*>(pa[t]);
        afl[0][t][1] = *reinterpret_cast<const float4*>(pa[t] + 4);
        bf[0][t] = *reinterpret_cast<const short8*>(pb[t]);
    }

#pragma unroll
    for (int kt = 0; kt < 4; ++kt) {
        const int cur = kt & 1, nxt = cur ^ 1;
        if (kt < 3) {
#pragma unroll
            for (int t = 0; t < 4; ++t) {
                afl[nxt][t][0] = *reinterpret_cast<const float4*>(pa[t] + (kt + 1) * 32);
                afl[nxt][t][1] = *reinterpret_cast<const float4*>(pa[t] + (kt + 1) * 32 + 4);
                bf[nxt][t] = *reinterpret_cast<const short8*>(pb[t] + (kt + 1) * 32);
            }
        }
        short8 a[4];
#pragma unroll
        for (int t = 0; t < 4; ++t) {
            float4 f0 = afl[cur][t][0], f1 = afl[cur][t][1];
            short8 av;
            av[0] = (short)f2b(f0.x); av[1] = (short)f2b(f0.y);
            av[2] = (short)f2b(f0.z); av[3] = (short)f2b(f0.w);
            av[4] = (short)f2b(f1.x); av[5] = (short)f2b(f1.y);
            av[6] = (short)f2b(f1.z); av[7] = (short)f2b(f1.w);
            a[t] = av;
        }
#pragma unroll
        for (int i = 0; i < 4; ++i)
#pragma unroll
            for (int j = 0; j < 4; ++j)
                acc[i][j] = __builtin_amdgcn_mfma_f32_16x16x32_bf16(a[i], bf[cur][j], acc[i][j], 0, 0, 0);
    }

#pragma unroll
    for (int i = 0; i < 4; ++i)
#pragma unroll
        for (int r = 0; r < 4; ++r) {
            int row = bm + i * 16 + quad * 4 + r;
            if (row >= M) continue;
            float dv = dinv[row];
#pragma unroll
            for (int j = 0; j < 4; ++j) {
                int col = bn + j * 16 + l16;
                Cout[(size_t)row * 128 + col] = f2b(acc[i][j][r] * dv);
            }
        }
}

// ---------------- gather v5: 8 load-groups in flight (32 rows/iter) --------
// Channels packed 2/dword; even channel = d<<16, odd = d & 0xffff0000 (both
// exact bf16->f32), float2 accumulators pair into v_pk_add_f32.

__global__ __launch_bounds__(256) void gather_k(
    const int2* __restrict__ rowptr2, const int* __restrict__ csr,
    const unsigned short* __restrict__ xws, const float* __restrict__ dinv,
    const float* __restrict__ x, const float* __restrict__ conv_b,
    unsigned short* __restrict__ h0)
{
    const int node = blockIdx.x * 4 + (threadIdx.x >> 6);
    if (node >= NNODES) return;
    const int lane = threadIdx.x & 63;
    const int sub = lane >> 4;
    const int c16 = lane & 15;

    const int2 se = rowptr2[node];
    const int start = se.x, end = se.y;

    float2 s2[4];
    if (sub == 0) {
        uint4 v = *reinterpret_cast<const uint4*>(xws + (size_t)node * CIN + c16 * 8);
        unsigned d[4] = {v.x, v.y, v.z, v.w};
#pragma unroll
        for (int k = 0; k < 4; ++k) {
            s2[k].x = __uint_as_float(d[k] << 16);
            s2[k].y = __uint_as_float(d[k] & 0xffff0000u);
        }
    } else {
#pragma unroll
        for (int k = 0; k < 4; ++k) s2[k] = make_float2(0.f, 0.f);
    }

    for (int p = start; p < end; p += 32) {
        uint4 r[8];
        int valid[8];
#pragma unroll
        for (int j = 0; j < 8; ++j) {
            int e = p + j * 4 + sub;
            bool a = e < end;
            int idx = a ? csr[e] : node;     // fallback hits hot line, not accumulated
            r[j] = *reinterpret_cast<const uint4*>(xws + (size_t)idx * CIN + c16 * 8);
            valid[j] = a;
        }
#pragma unroll
        for (int j = 0; j < 8; ++j)
            if (valid[j]) {
                unsigned d[4] = {r[j].x, r[j].y, r[j].z, r[j].w};
#pragma unroll
                for (int k = 0; k < 4; ++k) {
                    s2[k].x += __uint_as_float(d[k] << 16);
                    s2[k].y += __uint_as_float(d[k] & 0xffff0000u);
                }
            }
    }

    // reduce across the 4 sub-groups (lane bits 4,5)
#pragma unroll
    for (int k = 0; k < 4; ++k) {
        s2[k].x += __shfl_xor(s2[k].x, 16, 64);
        s2[k].y += __shfl_xor(s2[k].y, 16, 64);
        s2[k].x += __shfl_xor(s2[k].x, 32, 64);
        s2[k].y += __shfl_xor(s2[k].y, 32, 64);
    }

    if (sub == 0) {
        float dvv = dinv[node];
        float4 b0 = *reinterpret_cast<const float4*>(conv_b + c16 * 8);
        float4 b1 = *reinterpret_cast<const float4*>(conv_b + c16 * 8 + 4);
        float4 x0 = *reinterpret_cast<const float4*>(x + (size_t)node * CIN + c16 * 8);
        float4 x1 = *reinterpret_cast<const float4*>(x + (size_t)node * CIN + c16 * 8 + 4);
        float o[8];
        o[0] = fmaxf(s2[0].x * dvv + b0.x, 0.f) + x0.x;
        o[1] = fmaxf(s2[0].y * dvv + b0.y, 0.f) + x0.y;
        o[2] = fmaxf(s2[1].x * dvv + b0.z, 0.f) + x0.z;
        o[3] = fmaxf(s2[1].y * dvv + b0.w, 0.f) + x0.w;
        o[4] = fmaxf(s2[2].x * dvv + b1.x, 0.f) + x1.x;
        o[5] = fmaxf(s2[2].y * dvv + b1.y, 0.f) + x1.y;
        o[6] = fmaxf(s2[3].x * dvv + b1.z, 0.f) + x1.z;
        o[7] = fmaxf(s2[3].y * dvv + b1.w, 0.f) + x1.w;
        short8 pk;
#pragma unroll
        for (int q = 0; q < 8; ++q) pk[q] = (short)f2b(o[q]);
        *reinterpret_cast<short8*>(h0 + (size_t)node * CIN + c16 * 8) = pk;
    }
}

// ---------------- register-pipelined GEMM v2 (A 2-deep, B 1-deep) ----------
// MODE 1: C = relu(A@B^T + bias) -> bf16 Cout (stride 256)
// MODE 2: rowsum[row*4 + blockIdx.y*2 + (wave&1)] = partial w3-dot (64 cols)

template <int LDK, int KT, int MODE>
__global__ __launch_bounds__(256) void rgemm_k(
    const unsigned short* __restrict__ A, const unsigned short* __restrict__ B,
    const float* __restrict__ bias, const float* __restrict__ w3,
    unsigned short* __restrict__ Cout, float* __restrict__ rowsum, int M)
{
    const int tid = threadIdx.x;
    const int wave = tid >> 6;
    const int lane = tid & 63;
    const int quad = lane >> 4;
    const int l16 = lane & 15;
    const int rh = (wave >> 1) * 64;
    const int ch = (wave & 1) * 64;
    const int bm = blockIdx.x * 128;
    const int bn = blockIdx.y * 128;

    const unsigned short* pa[4];
    const unsigned short* pb[4];
#pragma unroll
    for (int t = 0; t < 4; ++t) {
        int m = bm + rh + t * 16 + l16; if (m >= M) m = M - 1;   // clamp; guarded at store
        pa[t] = A + (size_t)m * LDK + quad * 8;
        int n = bn + ch + t * 16 + l16;
        pb[t] = B + (size_t)n * LDK + quad * 8;
    }

    f32x4 acc[4][4];
#pragma unroll
    for (int i = 0; i < 4; ++i)
#pragma unroll
        for (int j = 0; j < 4; ++j) {
            f32x4 z = {0.f, 0.f, 0.f, 0.f};
            acc[i][j] = z;
        }

    short8 af[3][4], bf[2][4];
#pragma unroll
    for (int t = 0; t < 4; ++t) {
        af[0][t] = *reinterpret_cast<const short8*>(pa[t]);
        bf[0][t] = *reinterpret_cast<const short8*>(pb[t]);
        af[1][t] = *reinterpret_cast<const short8*>(pa[t] + 32);
    }

#pragma unroll
    for (int kt = 0; kt < KT; ++kt) {
        const int ca = kt % 3, na = (kt + 2) % 3;
        const int cb = kt & 1, nb = cb ^ 1;
        if (kt + 2 < KT) {
#pragma unroll
            for (int t = 0; t < 4; ++t)
                af[na][t] = *reinterpret_cast<const short8*>(pa[t] + (kt + 2) * 32);
        }
        if (kt + 1 < KT) {
#pragma unroll
            for (int t = 0; t < 4; ++t)
                bf[nb][t] = *reinterpret_cast<const short8*>(pb[t] + (kt + 1) * 32);
        }
#pragma unroll
        for (int i = 0; i < 4; ++i)
#pragma unroll
            for (int j = 0; j < 4; ++j)
                acc[i][j] = __builtin_amdgcn_mfma_f32_16x16x32_bf16(af[ca][i], bf[cb][j], acc[i][j], 0, 0, 0);
    }

    if (MODE == 1) {
#pragma unroll
        for (int nt = 0; nt < 4; ++nt) {
            int col = bn + ch + nt * 16 + l16;
            float bv = bias[col];
#pragma unroll
            for (int mt = 0; mt < 4; ++mt)
#pragma unroll
                for (int r = 0; r < 4; ++r) {
                    int row = bm + rh + mt * 16 + quad * 4 + r;
                    if (row < M)
                        Cout[(size_t)row * 256 + col] = f2b(fmaxf(acc[mt][nt][r] + bv, 0.f));
                }
        }
    } else {
        float part[4][4];
#pragma unroll
        for (int mt = 0; mt < 4; ++mt)
#pragma unroll
            for (int r = 0; r < 4; ++r) part[mt][r] = 0.f;
#pragma unroll
        for (int nt = 0; nt < 4; ++nt) {
            int col = bn + ch + nt * 16 + l16;
            float bs = bias[col];
            float wv3 = w3[col];
#pragma unroll
            for (int mt = 0; mt < 4; ++mt)
#pragma unroll
                for (int r = 0; r < 4; ++r)
                    part[mt][r] += fmaxf(acc[mt][nt][r] + bs, 0.f) * wv3;
        }
#pragma unroll
        for (int mt = 0; mt < 4; ++mt)
#pragma unroll
            for (int r = 0; r < 4; ++r) {
                float v = part[mt][r];
                v += __shfl_xor(v, 1, 64);
                v += __shfl_xor(v, 2, 64);
                v += __shfl_xor(v, 4, 64);
                v += __shfl_xor(v, 8, 64);
                part[mt][r] = v;
            }
        if (l16 == 0) {
            const int slot = blockIdx.y * 2 + (wave & 1);
#pragma unroll
            for (int mt = 0; mt < 4; ++mt)
#pragma unroll
                for (int r = 0; r < 4; ++r) {
                    int row = bm + rh + mt * 16 + quad * 4 + r;
                    if (row < M) rowsum[(size_t)row * 4 + slot] = part[mt][r];
                }
        }
    }
}

// ---------------- final: out[g] = b3 + sum of 80 rowsum slots ----------------

__global__ __launch_bounds__(256) void final_k(
    const float* __restrict__ rowsum, const float* __restrict__ b3,
    float* __restrict__ out)
{
    int g = blockIdx.x * 256 + threadIdx.x;
    if (g >= NGRAPH) return;
    const float4* p = reinterpret_cast<const float4*>(rowsum + (size_t)g * 80);
    float s = 0.f;
#pragma unroll
    for (int i = 0; i < 20; ++i) {
        float4 v = p[i];
        s += (v.x + v.y) + (v.z + v.w);
    }
    out[g] = s + b3[0];
}

// ---------------- launch ----------------

extern "C" void kernel_launch(void* const* d_in, const int* in_sizes, int n_in,
                              void* d_out, int out_size, void* d_ws, size_t ws_size,
                              hipStream_t stream)
{
    const float* x      = (const float*)d_in[0];
    const int*   ei     = (const int*)  d_in[1];
    const float* conv_w = (const float*)d_in[2];
    const float* conv_b = (const float*)d_in[3];
    const float* lin1_w = (const float*)d_in[4];
    const float* lin1_b = (const float*)d_in[5];
    const float* lin2_w = (const float*)d_in[6];
    const float* lin2_b = (const float*)d_in[7];
    const float* lin3_w = (const float*)d_in[8];
    const float* lin3_b = (const float*)d_in[9];
    float* out = (float*)d_out;

    // Workspace (~132 MB):
    //   h1 bf16 [N*256] | xws bf16 [N*128] | h0 bf16 [N*128]
    //   entries u32 [NB*CAP] | csr [NB*CAP] | rowptr2 | dinv | bfill
    //   wt0/wt1/wt2 | rowsum fp32 [100096*4]
    unsigned short* h1      = (unsigned short*)d_ws;
    unsigned short* xws     = h1 + (size_t)25600000;
    unsigned short* h0      = xws + (size_t)12800000;
    unsigned*       entries = (unsigned*)(h0 + (size_t)12800000);
    int*            csr     = (int*)(entries + (size_t)NB * CAP);
    int2*           rowptr2 = (int2*)(csr + (size_t)NB * CAP);
    float*          dinv    = (float*)(rowptr2 + NNODES);
    int*            bfill   = (int*)(dinv + NNODES);
    unsigned short* wt0     = (unsigned short*)(bfill + NB + 8);
    unsigned short* wt1     = wt0 + 16384;
    unsigned short* wt2     = wt1 + 32768;
    float*          rowsum  = (float*)(wt2 + 65536);

    // CSR build (fixed-capacity bucket windows)
    hipMemsetAsync(bfill, 0, NB * sizeof(int), stream);
    bin_k<<<BIN_WGS, 256, 0, stream>>>(ei, bfill, entries);
    bucket_build_k<<<NB, 256, 0, stream>>>(entries, bfill, rowptr2, csr, dinv);

    // weight conversions (one launch)
    cvt_w_k<<<(114688 + 255) / 256, 256, 0, stream>>>(conv_w, lin1_w, lin2_w, wt0, wt1, wt2);

    // gemm0: xws = (x @ conv_w) * dinv[row]
    mgemm0_k<<<(NNODES + 127) / 128, 256, 0, stream>>>(x, wt0, dinv, xws, NNODES);

    // gather + conv epilogue -> h0 bf16
    gather_k<<<(NNODES + 3) / 4, 256, 0, stream>>>(rowptr2, csr, xws, dinv, x, conv_b, h0);

    const int gm = (NNODES + 127) / 128;   // 782

    // gemm1: h1 = relu(h0 @ W1^T + b1)   (register-pipelined, A 2-deep)
    rgemm_k<128, 4, 1><<<dim3(gm, 2), 256, 0, stream>>>(h0, wt1, lin1_b, nullptr, h1, nullptr, NNODES);

    // gemm2 + fused w3-dot -> rowsum (4 slots/row, no atomics)
    rgemm_k<256, 8, 2><<<dim3(gm, 2), 256, 0, stream>>>(h1, wt2, lin2_b, lin3_w, nullptr, rowsum, NNODES);

    // out[g] = b3 + sum of this graph's 80 rowsum slots
    final_k<<<(NGRAPH + 255) / 256, 256, 0, stream>>>(rowsum, lin3_b, out);
}

// Round 12
// 310.717 us; speedup vs baseline: 1.2911x; 1.1703x over previous
//
#include <hip/hip_runtime.h>
#include <hip/hip_bf16.h>
#include <cstddef>

#define NNODES 100000
#define NEDGES 1600000
#define CIN 128
#define HID 256
#define ACT 20
#define NGRAPH (NNODES / ACT)
#define BSHIFT 8
#define NB ((NNODES + 255) >> 8)     // 391 buckets of 256 nodes
#define BIN_WGS 512
#define CAP 8192                     // bucket window capacity (mean fill 4096)

typedef __attribute__((ext_vector_type(8))) short short8;
typedef __attribute__((ext_vector_type(4))) float f32x4;

__device__ __forceinline__ unsigned short f2b(float f) {
    unsigned u = __float_as_uint(f);
    u += 0x7FFF + ((u >> 16) & 1);          // round-to-nearest-even
    return (unsigned short)(u >> 16);
}
__device__ __forceinline__ float b2f(unsigned short h) {
    return __uint_as_float(((unsigned)h) << 16);
}

// ---------------- bucketed CSR build (fixed-capacity windows) ----------------

__global__ __launch_bounds__(256) void bin_k(const int* __restrict__ ei,
                                             int* __restrict__ bfill,
                                             unsigned* __restrict__ entries) {
    __shared__ int cnt[NB], base[NB], cur[NB];
    for (int i = threadIdx.x; i < NB; i += 256) { cnt[i] = 0; cur[i] = 0; }
    __syncthreads();
    const int per = NEDGES / BIN_WGS;      // 3125
    const int s = blockIdx.x * per;
    const int e = s + per;
    for (int i = s + threadIdx.x; i < e; i += 256)
        atomicAdd(&cnt[ei[NEDGES + i] >> BSHIFT], 1);
    __syncthreads();
    for (int i = threadIdx.x; i < NB; i += 256)
        base[i] = cnt[i] ? atomicAdd(&bfill[i], cnt[i]) : 0;
    __syncthreads();
    for (int i = s + threadIdx.x; i < e; i += 256) {
        int src = ei[i], dst = ei[NEDGES + i];
        int b = dst >> BSHIFT;
        int r = base[b] + atomicAdd(&cur[b], 1);
        if (r < CAP)
            entries[(size_t)b * CAP + r] = ((unsigned)src << 8) | (unsigned)(dst & 255);
    }
}

__global__ __launch_bounds__(256) void bucket_build_k(
    const unsigned* __restrict__ entries, const int* __restrict__ bfill,
    int2* __restrict__ rowptr2, int* __restrict__ csr, float* __restrict__ dinv) {
    const int b = blockIdx.x;
    const int count = min(bfill[b], CAP);
    const int node0 = b << BSHIFT;
    const int nn = min(256, NNODES - node0);
    const size_t gbase = (size_t)b * CAP;
    __shared__ int cnt[256], off[256], cur[256];
    const int t = threadIdx.x;
    cnt[t] = 0; cur[t] = 0;
    __syncthreads();
    for (int i = t; i < count; i += 256)
        atomicAdd(&cnt[entries[gbase + i] & 255], 1);
    __syncthreads();
    int lane = t & 63, wid = t >> 6;
    int v = cnt[t];
    int inc = v;
#pragma unroll
    for (int o = 1; o < 64; o <<= 1) {
        int tv = __shfl_up(inc, o, 64);
        if (lane >= o) inc += tv;
    }
    __shared__ int wsum[4];
    if (lane == 63) wsum[wid] = inc;
    __syncthreads();
    int woff = 0;
#pragma unroll
    for (int w = 0; w < 4; ++w) woff += (w < wid) ? wsum[w] : 0;
    int excl = inc + woff - v;
    off[t] = excl;
    if (t < nn) {
        rowptr2[node0 + t] = make_int2((int)gbase + excl, (int)gbase + excl + v);
        dinv[node0 + t] = rsqrtf(1.0f + (float)v);
    }
    __syncthreads();
    for (int i = t; i < count; i += 256) {
        unsigned en = entries[gbase + i];
        int loc = (int)(en & 255);
        int r = atomicAdd(&cur[loc], 1);
        csr[gbase + off[loc] + r] = (int)(en >> 8);
    }
}

// ---------------- weight conversions (single launch) ----------------

__global__ void cvt_w_k(const float* __restrict__ conv_w,
                        const float* __restrict__ lin1_w,
                        const float* __restrict__ lin2_w,
                        unsigned short* __restrict__ wt0,
                        unsigned short* __restrict__ wt1,
                        unsigned short* __restrict__ wt2) {
    int id = blockIdx.x * 256 + threadIdx.x;
    if (id < 16384) {
        int k = id >> 7, n = id & 127;
        wt0[n * 128 + k] = f2b(conv_w[k * 128 + n]);
    } else if (id < 16384 + 32768) {
        int i = id - 16384;
        wt1[i] = f2b(lin1_w[i]);
    } else if (id < 16384 + 32768 + 65536) {
        int i = id - 49152;
        wt2[i] = f2b(lin2_w[i]);
    }
}

// ---------------- MFMA bf16 GEMM for conv (fp32 A, reg-pipelined) ----------

__global__ __launch_bounds__(256) void mgemm0_k(
    const float* __restrict__ Af, const unsigned short* __restrict__ B,
    const float* __restrict__ dinv, unsigned short* __restrict__ Cout, int M)
{
    const int tid = threadIdx.x;
    const int wid = tid >> 6;
    const int lane = tid & 63;
    const int quad = lane >> 4;
    const int l16 = lane & 15;
    const int bm = blockIdx.x * 128 + (wid >> 1) * 64;
    const int bn = (wid & 1) * 64;

    const float* pa[4];
    const unsigned short* pb[4];
#pragma unroll
    for (int t = 0; t < 4; ++t) {
        int m = bm + t * 16 + l16; if (m >= M) m = M - 1;   // clamp; store guarded
        pa[t] = Af + (size_t)m * 128 + quad * 8;
        int n = bn + t * 16 + l16;
        pb[t] = B + (size_t)n * 128 + quad * 8;
    }

    f32x4 acc[4][4];
#pragma unroll
    for (int i = 0; i < 4; ++i)
#pragma unroll
        for (int j = 0; j < 4; ++j) {
            f32x4 z = {0.f, 0.f, 0.f, 0.f};
            acc[i][j] = z;
        }

    float4 afl[2][4][2];
    short8 bf[2][4];
#pragma unroll
    for (int t = 0; t < 4; ++t) {
        afl[0][t][0] = *reinterpret_cast<const float4*>(pa[t]);
        afl[0][t][1] = *reinterpret_cast<const float4*>(pa[t] + 4);
        bf[0][t] = *reinterpret_cast<const short8*>(pb[t]);
    }

#pragma unroll
    for (int kt = 0; kt < 4; ++kt) {
        const int cur = kt & 1, nxt = cur ^ 1;
        if (kt < 3) {
#pragma unroll
            for (int t = 0; t < 4; ++t) {
                afl[nxt][t][0] = *reinterpret_cast<const float4*>(pa[t] + (kt + 1) * 32);
                afl[nxt][t][1] = *reinterpret_cast<const float4*>(pa[t] + (kt + 1) * 32 + 4);
                bf[nxt][t] = *reinterpret_cast<const short8*>(pb[t] + (kt + 1) * 32);
            }
        }
        short8 a[4];
#pragma unroll
        for (int t = 0; t < 4; ++t) {
            float4 f0 = afl[cur][t][0], f1 = afl[cur][t][1];
            short8 av;
            av[0] = (short)f2b(f0.x); av[1] = (short)f2b(f0.y);
            av[2] = (short)f2b(f0.z); av[3] = (short)f2b(f0.w);
            av[4] = (short)f2b(f1.x); av[5] = (short)f2b(f1.y);
            av[6] = (short)f2b(f1.z); av[7] = (short)f2b(f1.w);
            a[t] = av;
        }
#pragma unroll
        for (int i = 0; i < 4; ++i)
#pragma unroll
            for (int j = 0; j < 4; ++j)
                acc[i][j] = __builtin_amdgcn_mfma_f32_16x16x32_bf16(a[i], bf[cur][j], acc[i][j], 0, 0, 0);
    }

#pragma unroll
    for (int i = 0; i < 4; ++i)
#pragma unroll
        for (int r = 0; r < 4; ++r) {
            int row = bm + i * 16 + quad * 4 + r;
            if (row >= M) continue;
            float dv = dinv[row];
#pragma unroll
            for (int j = 0; j < 4; ++j) {
                int col = bn + j * 16 + l16;
                Cout[(size_t)row * 128 + col] = f2b(acc[i][j][r] * dv);
            }
        }
}

// ---------------- gather v5 (at fabric roofline; unchanged) ----------------

__global__ __launch_bounds__(256) void gather_k(
    const int2* __restrict__ rowptr2, const int* __restrict__ csr,
    const unsigned short* __restrict__ xws, const float* __restrict__ dinv,
    const float* __restrict__ x, const float* __restrict__ conv_b,
    unsigned short* __restrict__ h0)
{
    const int node = blockIdx.x * 4 + (threadIdx.x >> 6);
    if (node >= NNODES) return;
    const int lane = threadIdx.x & 63;
    const int sub = lane >> 4;
    const int c16 = lane & 15;

    const int2 se = rowptr2[node];
    const int start = se.x, end = se.y;

    float2 s2[4];
    if (sub == 0) {
        uint4 v = *reinterpret_cast<const uint4*>(xws + (size_t)node * CIN + c16 * 8);
        unsigned d[4] = {v.x, v.y, v.z, v.w};
#pragma unroll
        for (int k = 0; k < 4; ++k) {
            s2[k].x = __uint_as_float(d[k] << 16);
            s2[k].y = __uint_as_float(d[k] & 0xffff0000u);
        }
    } else {
#pragma unroll
        for (int k = 0; k < 4; ++k) s2[k] = make_float2(0.f, 0.f);
    }

    for (int p = start; p < end; p += 32) {
        uint4 r[8];
        int valid[8];
#pragma unroll
        for (int j = 0; j < 8; ++j) {
            int e = p + j * 4 + sub;
            bool a = e < end;
            int idx = a ? csr[e] : node;
            r[j] = *reinterpret_cast<const uint4*>(xws + (size_t)idx * CIN + c16 * 8);
            valid[j] = a;
        }
#pragma unroll
        for (int j = 0; j < 8; ++j)
            if (valid[j]) {
                unsigned d[4] = {r[j].x, r[j].y, r[j].z, r[j].w};
#pragma unroll
                for (int k = 0; k < 4; ++k) {
                    s2[k].x += __uint_as_float(d[k] << 16);
                    s2[k].y += __uint_as_float(d[k] & 0xffff0000u);
                }
            }
    }

#pragma unroll
    for (int k = 0; k < 4; ++k) {
        s2[k].x += __shfl_xor(s2[k].x, 16, 64);
        s2[k].y += __shfl_xor(s2[k].y, 16, 64);
        s2[k].x += __shfl_xor(s2[k].x, 32, 64);
        s2[k].y += __shfl_xor(s2[k].y, 32, 64);
    }

    if (sub == 0) {
        float dvv = dinv[node];
        float4 b0 = *reinterpret_cast<const float4*>(conv_b + c16 * 8);
        float4 b1 = *reinterpret_cast<const float4*>(conv_b + c16 * 8 + 4);
        float4 x0 = *reinterpret_cast<const float4*>(x + (size_t)node * CIN + c16 * 8);
        float4 x1 = *reinterpret_cast<const float4*>(x + (size_t)node * CIN + c16 * 8 + 4);
        float o[8];
        o[0] = fmaxf(s2[0].x * dvv + b0.x, 0.f) + x0.x;
        o[1] = fmaxf(s2[0].y * dvv + b0.y, 0.f) + x0.y;
        o[2] = fmaxf(s2[1].x * dvv + b0.z, 0.f) + x0.z;
        o[3] = fmaxf(s2[1].y * dvv + b0.w, 0.f) + x0.w;
        o[4] = fmaxf(s2[2].x * dvv + b1.x, 0.f) + x1.x;
        o[5] = fmaxf(s2[2].y * dvv + b1.y, 0.f) + x1.y;
        o[6] = fmaxf(s2[3].x * dvv + b1.z, 0.f) + x1.z;
        o[7] = fmaxf(s2[3].y * dvv + b1.w, 0.f) + x1.w;
        short8 pk;
#pragma unroll
        for (int q = 0; q < 8; ++q) pk[q] = (short)f2b(o[q]);
        *reinterpret_cast<short8*>(h0 + (size_t)node * CIN + c16 * 8) = pk;
    }
}

// ---------------- fused MLP v3: reg-pipelined phases + 32 KB LDS h1 --------
// 64 rows/block, 256 thr. Phase 1: wave w computes h1[64][w*64..] with
// 1-deep reg prefetch of A (h0) and B (w1); relu+bias -> swizzled LDS.
// Phase 2: K=256; A-frags ds_read from LDS (1-deep prefetch), B (w2) global
// (1-deep prefetch). Fused epilogue: rowsum[row*4+wave] = partial w3-dot.
// vs round-6 mlp_k (155us): adds the round-10-proven global-load pipelining
// and halves LDS (32 KB -> 5 blocks/CU LDS-limit instead of 2).

__global__ __launch_bounds__(256) void fmlp_k(
    const unsigned short* __restrict__ h0, const unsigned short* __restrict__ w1,
    const float* __restrict__ b1, const unsigned short* __restrict__ w2,
    const float* __restrict__ b2, const float* __restrict__ w3,
    float* __restrict__ rowsum, int M)
{
    __shared__ unsigned short h1s[64 * 256];   // 32 KB, xor-swizzled
    const int tid = threadIdx.x;
    const int wave = tid >> 6;
    const int lane = tid & 63;
    const int quad = lane >> 4;
    const int l16 = lane & 15;
    const int bm = blockIdx.x * 64;
    const int nc0 = wave * 64;

    f32x4 acc[4][4];
#pragma unroll
    for (int i = 0; i < 4; ++i)
#pragma unroll
        for (int j = 0; j < 4; ++j) {
            f32x4 z = {0.f, 0.f, 0.f, 0.f};
            acc[i][j] = z;
        }

    // ---- phase 1: h1 = relu(h0 @ W1^T + b1), K=128 ----
    {
        const unsigned short* pa[4];
        const unsigned short* pb[4];
#pragma unroll
        for (int t = 0; t < 4; ++t) {
            int m = bm + t * 16 + l16; if (m >= M) m = M - 1;
            pa[t] = h0 + (size_t)m * 128 + quad * 8;
            int n = nc0 + t * 16 + l16;
            pb[t] = w1 + (size_t)n * 128 + quad * 8;
        }
        short8 af[2][4], bf[2][4];
#pragma unroll
        for (int t = 0; t < 4; ++t) {
            af[0][t] = *reinterpret_cast<const short8*>(pa[t]);
            bf[0][t] = *reinterpret_cast<const short8*>(pb[t]);
        }
#pragma unroll
        for (int kt = 0; kt < 4; ++kt) {
            const int cur = kt & 1, nxt = cur ^ 1;
            if (kt < 3) {
#pragma unroll
                for (int t = 0; t < 4; ++t) {
                    af[nxt][t] = *reinterpret_cast<const short8*>(pa[t] + (kt + 1) * 32);
                    bf[nxt][t] = *reinterpret_cast<const short8*>(pb[t] + (kt + 1) * 32);
                }
            }
#pragma unroll
            for (int i = 0; i < 4; ++i)
#pragma unroll
                for (int j = 0; j < 4; ++j)
                    acc[i][j] = __builtin_amdgcn_mfma_f32_16x16x32_bf16(af[cur][i], bf[cur][j], acc[i][j], 0, 0, 0);
        }
        // relu+bias -> swizzled LDS: (row, col) at row*256 + (((col>>3)^(row&7))<<3 | (col&7))
#pragma unroll
        for (int nt = 0; nt < 4; ++nt) {
            int col = nc0 + nt * 16 + l16;
            float bv = b1[col];
            int chunk = col >> 3, rem = col & 7;
#pragma unroll
            for (int mt = 0; mt < 4; ++mt)
#pragma unroll
                for (int r = 0; r < 4; ++r) {
                    int row = mt * 16 + quad * 4 + r;
                    h1s[row * 256 + (((chunk ^ (row & 7)) << 3) | rem)] =
                        f2b(fmaxf(acc[mt][nt][r] + bv, 0.f));
                }
        }
    }
    __syncthreads();

    // ---- phase 2: h2 = relu(h1s @ W2^T + b2), K=256 ----
#pragma unroll
    for (int i = 0; i < 4; ++i)
#pragma unroll
        for (int j = 0; j < 4; ++j) {
            f32x4 z = {0.f, 0.f, 0.f, 0.f};
            acc[i][j] = z;
        }
    {
        const unsigned short* pb[4];
#pragma unroll
        for (int t = 0; t < 4; ++t) {
            int n = nc0 + t * 16 + l16;
            pb[t] = w2 + (size_t)n * 256 + quad * 8;
        }
        short8 af[2][4], bf[2][4];
#pragma unroll
        for (int t = 0; t < 4; ++t) {
            int row = t * 16 + l16;
            af[0][t] = *reinterpret_cast<const short8*>(
                &h1s[row * 256 + (((quad ^ (row & 7)) << 3))]);
            bf[0][t] = *reinterpret_cast<const short8*>(pb[t]);
        }
#pragma unroll
        for (int kt = 0; kt < 8; ++kt) {
            const int cur = kt & 1, nxt = cur ^ 1;
            if (kt < 7) {
                const int c1 = (kt + 1) * 4 + quad;
#pragma unroll
                for (int t = 0; t < 4; ++t) {
                    int row = t * 16 + l16;
                    af[nxt][t] = *reinterpret_cast<const short8*>(
                        &h1s[row * 256 + ((c1 ^ (row & 7)) << 3)]);
                    bf[nxt][t] = *reinterpret_cast<const short8*>(pb[t] + (kt + 1) * 32);
                }
            }
#pragma unroll
            for (int i = 0; i < 4; ++i)
#pragma unroll
                for (int j = 0; j < 4; ++j)
                    acc[i][j] = __builtin_amdgcn_mfma_f32_16x16x32_bf16(af[cur][i], bf[cur][j], acc[i][j], 0, 0, 0);
        }
    }

    // ---- fused epilogue: partial w3-dot over this wave's 64 cols ----
    float part[4][4];
#pragma unroll
    for (int mt = 0; mt < 4; ++mt)
#pragma unroll
        for (int r = 0; r < 4; ++r) part[mt][r] = 0.f;
#pragma unroll
    for (int nt = 0; nt < 4; ++nt) {
        int col = nc0 + nt * 16 + l16;
        float bs = b2[col];
        float wv3 = w3[col];
#pragma unroll
        for (int mt = 0; mt < 4; ++mt)
#pragma unroll
            for (int r = 0; r < 4; ++r)
                part[mt][r] += fmaxf(acc[mt][nt][r] + bs, 0.f) * wv3;
    }
#pragma unroll
    for (int mt = 0; mt < 4; ++mt)
#pragma unroll
        for (int r = 0; r < 4; ++r) {
            float v = part[mt][r];
            v += __shfl_xor(v, 1, 64);
            v += __shfl_xor(v, 2, 64);
            v += __shfl_xor(v, 4, 64);
            v += __shfl_xor(v, 8, 64);
            part[mt][r] = v;
        }
    if (l16 == 0) {
#pragma unroll
        for (int mt = 0; mt < 4; ++mt)
#pragma unroll
            for (int r = 0; r < 4; ++r) {
                int row = bm + mt * 16 + quad * 4 + r;
                if (row < M) rowsum[(size_t)row * 4 + wave] = part[mt][r];
            }
    }
}

// ---------------- final: out[g] = b3 + sum of 80 rowsum slots ----------------

__global__ __launch_bounds__(256) void final_k(
    const float* __restrict__ rowsum, const float* __restrict__ b3,
    float* __restrict__ out)
{
    int g = blockIdx.x * 256 + threadIdx.x;
    if (g >= NGRAPH) return;
    const float4* p = reinterpret_cast<const float4*>(rowsum + (size_t)g * 80);
    float s = 0.f;
#pragma unroll
    for (int i = 0; i < 20; ++i) {
        float4 v = p[i];
        s += (v.x + v.y) + (v.z + v.w);
    }
    out[g] = s + b3[0];
}

// ---------------- launch ----------------

extern "C" void kernel_launch(void* const* d_in, const int* in_sizes, int n_in,
                              void* d_out, int out_size, void* d_ws, size_t ws_size,
                              hipStream_t stream)
{
    const float* x      = (const float*)d_in[0];
    const int*   ei     = (const int*)  d_in[1];
    const float* conv_w = (const float*)d_in[2];
    const float* conv_b = (const float*)d_in[3];
    const float* lin1_w = (const float*)d_in[4];
    const float* lin1_b = (const float*)d_in[5];
    const float* lin2_w = (const float*)d_in[6];
    const float* lin2_b = (const float*)d_in[7];
    const float* lin3_w = (const float*)d_in[8];
    const float* lin3_b = (const float*)d_in[9];
    float* out = (float*)d_out;

    // Workspace (~81 MB):
    //   xws bf16 [N*128] | h0 bf16 [N*128] | entries u32 [NB*CAP] | csr [NB*CAP]
    //   rowptr2 int2 [N] | dinv [N] | bfill [NB] | wt0/wt1/wt2 | rowsum [100096*4]
    unsigned short* xws     = (unsigned short*)d_ws;
    unsigned short* h0      = xws + (size_t)12800000;
    unsigned*       entries = (unsigned*)(h0 + (size_t)12800000);
    int*            csr     = (int*)(entries + (size_t)NB * CAP);
    int2*           rowptr2 = (int2*)(csr + (size_t)NB * CAP);
    float*          dinv    = (float*)(rowptr2 + NNODES);
    int*            bfill   = (int*)(dinv + NNODES);
    unsigned short* wt0     = (unsigned short*)(bfill + NB + 8);
    unsigned short* wt1     = wt0 + 16384;
    unsigned short* wt2     = wt1 + 32768;
    float*          rowsum  = (float*)(wt2 + 65536);

    // CSR build (fixed-capacity bucket windows)
    hipMemsetAsync(bfill, 0, NB * sizeof(int), stream);
    bin_k<<<BIN_WGS, 256, 0, stream>>>(ei, bfill, entries);
    bucket_build_k<<<NB, 256, 0, stream>>>(entries, bfill, rowptr2, csr, dinv);

    // weight conversions (one launch)
    cvt_w_k<<<(114688 + 255) / 256, 256, 0, stream>>>(conv_w, lin1_w, lin2_w, wt0, wt1, wt2);

    // gemm0: xws = (x @ conv_w) * dinv[row]
    mgemm0_k<<<(NNODES + 127) / 128, 256, 0, stream>>>(x, wt0, dinv, xws, NNODES);

    // gather + conv epilogue -> h0 bf16
    gather_k<<<(NNODES + 3) / 4, 256, 0, stream>>>(rowptr2, csr, xws, dinv, x, conv_b, h0);

    // fused MLP: gemm1 -> LDS -> gemm2 -> w3-dot -> rowsum (no h1 round-trip)
    fmlp_k<<<(NNODES + 63) / 64, 256, 0, stream>>>(h0, wt1, lin1_b, wt2, lin2_b, lin3_w,
                                                   rowsum, NNODES);

    // out[g] = b3 + sum of this graph's 80 rowsum slots
    final_k<<<(NGRAPH + 255) / 256, 256, 0, stream>>>(rowsum, lin3_b, out);
}

// Round 13
// 308.324 us; speedup vs baseline: 1.3011x; 1.0078x over previous
//
#include <hip/hip_runtime.h>
#include <hip/hip_bf16.h>
#include <cstddef>

#define NNODES 100000
#define NEDGES 1600000
#define CIN 128
#define HID 256
#define ACT 20
#define NGRAPH (NNODES / ACT)
#define BSHIFT 8
#define NB ((NNODES + 255) >> 8)     // 391 buckets of 256 nodes
#define BIN_WGS 512
#define PER_WG (NEDGES / BIN_WGS)    // 3125
#define CAP 8192                     // bucket window capacity (mean fill 4096)

typedef __attribute__((ext_vector_type(8))) short short8;
typedef __attribute__((ext_vector_type(4))) float f32x4;

__device__ __forceinline__ unsigned short f2b(float f) {
    unsigned u = __float_as_uint(f);
    u += 0x7FFF + ((u >> 16) & 1);          // round-to-nearest-even
    return (unsigned short)(u >> 16);
}
__device__ __forceinline__ float b2f(unsigned short h) {
    return __uint_as_float(((unsigned)h) << 16);
}

// ---------------- bucketed CSR build (fixed-capacity windows) ----------------
// bin_k v3: bucket-sort the wg's 3125 edges in LDS first, then write the
// bucket-contiguous runs with a linear sweep -> run-coalesced global stores
// (vs per-edge scattered 4B stores that each touch a 64B line).

__global__ __launch_bounds__(256) void bin_k(const int* __restrict__ ei,
                                             int* __restrict__ bfill,
                                             unsigned* __restrict__ entries) {
    __shared__ int cnt[NB], lofs[NB], base[NB], cur[NB];
    __shared__ unsigned lbuf[PER_WG];
    __shared__ int gdst[PER_WG];
    __shared__ int wsum[4];
    const int t = threadIdx.x;
    for (int i = t; i < NB; i += 256) { cnt[i] = 0; cur[i] = 0; }
    __syncthreads();
    const int s = blockIdx.x * PER_WG;
    const int e = s + PER_WG;
    for (int i = s + t; i < e; i += 256)
        atomicAdd(&cnt[ei[NEDGES + i] >> BSHIFT], 1);
    __syncthreads();
    // exclusive scan over NB buckets (pairs: thread t owns 2t, 2t+1)
    int c0 = (2 * t < NB) ? cnt[2 * t] : 0;
    int c1 = (2 * t + 1 < NB) ? cnt[2 * t + 1] : 0;
    int v = c0 + c1;
    int lane = t & 63, wid = t >> 6;
    int inc = v;
#pragma unroll
    for (int o = 1; o < 64; o <<= 1) {
        int tv = __shfl_up(inc, o, 64);
        if (lane >= o) inc += tv;
    }
    if (lane == 63) wsum[wid] = inc;
    __syncthreads();
    int woff = 0;
#pragma unroll
    for (int w = 0; w < 4; ++w) woff += (w < wid) ? wsum[w] : 0;
    int excl = inc + woff - v;
    if (2 * t < NB) lofs[2 * t] = excl;
    if (2 * t + 1 < NB) lofs[2 * t + 1] = excl + c0;
    __syncthreads();
    // reserve global space per bucket
    for (int b = t; b < NB; b += 256)
        base[b] = cnt[b] ? atomicAdd(&bfill[b], cnt[b]) : 0;
    __syncthreads();
    // place edges into bucket-sorted LDS buffer + precompute global slots
    for (int i = s + t; i < e; i += 256) {
        int src = ei[i], dst = ei[NEDGES + i];
        int b = dst >> BSHIFT;
        int r = atomicAdd(&cur[b], 1);
        int slot = lofs[b] + r;
        lbuf[slot] = ((unsigned)src << 8) | (unsigned)(dst & 255);
        int g = base[b] + r;
        gdst[slot] = (g < CAP) ? (int)((size_t)b * CAP + g) : -1;
    }
    __syncthreads();
    // linear sweep: consecutive lanes -> consecutive addresses within runs
    for (int i = t; i < PER_WG; i += 256) {
        int g = gdst[i];
        if (g >= 0) entries[g] = lbuf[i];
    }
}

__global__ __launch_bounds__(256) void bucket_build_k(
    const unsigned* __restrict__ entries, const int* __restrict__ bfill,
    int2* __restrict__ rowptr2, int* __restrict__ csr, float* __restrict__ dinv) {
    const int b = blockIdx.x;
    const int count = min(bfill[b], CAP);
    const int node0 = b << BSHIFT;
    const int nn = min(256, NNODES - node0);
    const size_t gbase = (size_t)b * CAP;
    __shared__ int cnt[256], off[256], cur[256];
    const int t = threadIdx.x;
    cnt[t] = 0; cur[t] = 0;
    __syncthreads();
    for (int i = t; i < count; i += 256)
        atomicAdd(&cnt[entries[gbase + i] & 255], 1);
    __syncthreads();
    int lane = t & 63, wid = t >> 6;
    int v = cnt[t];
    int inc = v;
#pragma unroll
    for (int o = 1; o < 64; o <<= 1) {
        int tv = __shfl_up(inc, o, 64);
        if (lane >= o) inc += tv;
    }
    __shared__ int wsum[4];
    if (lane == 63) wsum[wid] = inc;
    __syncthreads();
    int woff = 0;
#pragma unroll
    for (int w = 0; w < 4; ++w) woff += (w < wid) ? wsum[w] : 0;
    int excl = inc + woff - v;
    off[t] = excl;
    if (t < nn) {
        rowptr2[node0 + t] = make_int2((int)gbase + excl, (int)gbase + excl + v);
        dinv[node0 + t] = rsqrtf(1.0f + (float)v);
    }
    __syncthreads();
    for (int i = t; i < count; i += 256) {
        unsigned en = entries[gbase + i];
        int loc = (int)(en & 255);
        int r = atomicAdd(&cur[loc], 1);
        csr[gbase + off[loc] + r] = (int)(en >> 8);
    }
}

// ---------------- weight conversions (single launch) ----------------

__global__ void cvt_w_k(const float* __restrict__ conv_w,
                        const float* __restrict__ lin1_w,
                        const float* __restrict__ lin2_w,
                        unsigned short* __restrict__ wt0,
                        unsigned short* __restrict__ wt1,
                        unsigned short* __restrict__ wt2) {
    int id = blockIdx.x * 256 + threadIdx.x;
    if (id < 16384) {
        int k = id >> 7, n = id & 127;
        wt0[n * 128 + k] = f2b(conv_w[k * 128 + n]);
    } else if (id < 16384 + 32768) {
        int i = id - 16384;
        wt1[i] = f2b(lin1_w[i]);
    } else if (id < 16384 + 32768 + 65536) {
        int i = id - 49152;
        wt2[i] = f2b(lin2_w[i]);
    }
}

// ---------------- MFMA bf16 GEMM for conv (fp32 A, reg-pipelined) ----------

__global__ __launch_bounds__(256) void mgemm0_k(
    const float* __restrict__ Af, const unsigned short* __restrict__ B,
    const float* __restrict__ dinv, unsigned short* __restrict__ Cout, int M)
{
    const int tid = threadIdx.x;
    const int wid = tid >> 6;
    const int lane = tid & 63;
    const int quad = lane >> 4;
    const int l16 = lane & 15;
    const int bm = blockIdx.x * 128 + (wid >> 1) * 64;
    const int bn = (wid & 1) * 64;

    const float* pa[4];
    const unsigned short* pb[4];
#pragma unroll
    for (int t = 0; t < 4; ++t) {
        int m = bm + t * 16 + l16; if (m >= M) m = M - 1;   // clamp; store guarded
        pa[t] = Af + (size_t)m * 128 + quad * 8;
        int n = bn + t * 16 + l16;
        pb[t] = B + (size_t)n * 128 + quad * 8;
    }

    f32x4 acc[4][4];
#pragma unroll
    for (int i = 0; i < 4; ++i)
#pragma unroll
        for (int j = 0; j < 4; ++j) {
            f32x4 z = {0.f, 0.f, 0.f, 0.f};
            acc[i][j] = z;
        }

    float4 afl[2][4][2];
    short8 bf[2][4];
#pragma unroll
    for (int t = 0; t < 4; ++t) {
        afl[0][t][0] = *reinterpret_cast<const float4*>(pa[t]);
        afl[0][t][1] = *reinterpret_cast<const float4*>(pa[t] + 4);
        bf[0][t] = *reinterpret_cast<const short8*>(pb[t]);
    }

#pragma unroll
    for (int kt = 0; kt < 4; ++kt) {
        const int cur = kt & 1, nxt = cur ^ 1;
        if (kt < 3) {
#pragma unroll
            for (int t = 0; t < 4; ++t) {
                afl[nxt][t][0] = *reinterpret_cast<const float4*>(pa[t] + (kt + 1) * 32);
                afl[nxt][t][1] = *reinterpret_cast<const float4*>(pa[t] + (kt + 1) * 32 + 4);
                bf[nxt][t] = *reinterpret_cast<const short8*>(pb[t] + (kt + 1) * 32);
            }
        }
        short8 a[4];
#pragma unroll
        for (int t = 0; t < 4; ++t) {
            float4 f0 = afl[cur][t][0], f1 = afl[cur][t][1];
            short8 av;
            av[0] = (short)f2b(f0.x); av[1] = (short)f2b(f0.y);
            av[2] = (short)f2b(f0.z); av[3] = (short)f2b(f0.w);
            av[4] = (short)f2b(f1.x); av[5] = (short)f2b(f1.y);
            av[6] = (short)f2b(f1.z); av[7] = (short)f2b(f1.w);
            a[t] = av;
        }
#pragma unroll
        for (int i = 0; i < 4; ++i)
#pragma unroll
            for (int j = 0; j < 4; ++j)
                acc[i][j] = __builtin_amdgcn_mfma_f32_16x16x32_bf16(a[i], bf[cur][j], acc[i][j], 0, 0, 0);
    }

#pragma unroll
    for (int i = 0; i < 4; ++i)
#pragma unroll
        for (int r = 0; r < 4; ++r) {
            int row = bm + i * 16 + quad * 4 + r;
            if (row >= M) continue;
            float dv = dinv[row];
#pragma unroll
            for (int j = 0; j < 4; ++j) {
                int col = bn + j * 16 + l16;
                Cout[(size_t)row * 128 + col] = f2b(acc[i][j][r] * dv);
            }
        }
}

// ---------------- gather v5 (at fabric roofline; unchanged) ----------------

__global__ __launch_bounds__(256) void gather_k(
    const int2* __restrict__ rowptr2, const int* __restrict__ csr,
    const unsigned short* __restrict__ xws, const float* __restrict__ dinv,
    const float* __restrict__ x, const float* __restrict__ conv_b,
    unsigned short* __restrict__ h0)
{
    const int node = blockIdx.x * 4 + (threadIdx.x >> 6);
    if (node >= NNODES) return;
    const int lane = threadIdx.x & 63;
    const int sub = lane >> 4;
    const int c16 = lane & 15;

    const int2 se = rowptr2[node];
    const int start = se.x, end = se.y;

    float2 s2[4];
    if (sub == 0) {
        uint4 v = *reinterpret_cast<const uint4*>(xws + (size_t)node * CIN + c16 * 8);
        unsigned d[4] = {v.x, v.y, v.z, v.w};
#pragma unroll
        for (int k = 0; k < 4; ++k) {
            s2[k].x = __uint_as_float(d[k] << 16);
            s2[k].y = __uint_as_float(d[k] & 0xffff0000u);
        }
    } else {
#pragma unroll
        for (int k = 0; k < 4; ++k) s2[k] = make_float2(0.f, 0.f);
    }

    for (int p = start; p < end; p += 32) {
        uint4 r[8];
        int valid[8];
#pragma unroll
        for (int j = 0; j < 8; ++j) {
            int e = p + j * 4 + sub;
            bool a = e < end;
            int idx = a ? csr[e] : node;
            r[j] = *reinterpret_cast<const uint4*>(xws + (size_t)idx * CIN + c16 * 8);
            valid[j] = a;
        }
#pragma unroll
        for (int j = 0; j < 8; ++j)
            if (valid[j]) {
                unsigned d[4] = {r[j].x, r[j].y, r[j].z, r[j].w};
#pragma unroll
                for (int k = 0; k < 4; ++k) {
                    s2[k].x += __uint_as_float(d[k] << 16);
                    s2[k].y += __uint_as_float(d[k] & 0xffff0000u);
                }
            }
    }

#pragma unroll
    for (int k = 0; k < 4; ++k) {
        s2[k].x += __shfl_xor(s2[k].x, 16, 64);
        s2[k].y += __shfl_xor(s2[k].y, 16, 64);
        s2[k].x += __shfl_xor(s2[k].x, 32, 64);
        s2[k].y += __shfl_xor(s2[k].y, 32, 64);
    }

    if (sub == 0) {
        float dvv = dinv[node];
        float4 b0 = *reinterpret_cast<const float4*>(conv_b + c16 * 8);
        float4 b1 = *reinterpret_cast<const float4*>(conv_b + c16 * 8 + 4);
        float4 x0 = *reinterpret_cast<const float4*>(x + (size_t)node * CIN + c16 * 8);
        float4 x1 = *reinterpret_cast<const float4*>(x + (size_t)node * CIN + c16 * 8 + 4);
        float o[8];
        o[0] = fmaxf(s2[0].x * dvv + b0.x, 0.f) + x0.x;
        o[1] = fmaxf(s2[0].y * dvv + b0.y, 0.f) + x0.y;
        o[2] = fmaxf(s2[1].x * dvv + b0.z, 0.f) + x0.z;
        o[3] = fmaxf(s2[1].y * dvv + b0.w, 0.f) + x0.w;
        o[4] = fmaxf(s2[2].x * dvv + b1.x, 0.f) + x1.x;
        o[5] = fmaxf(s2[2].y * dvv + b1.y, 0.f) + x1.y;
        o[6] = fmaxf(s2[3].x * dvv + b1.z, 0.f) + x1.z;
        o[7] = fmaxf(s2[3].y * dvv + b1.w, 0.f) + x1.w;
        short8 pk;
#pragma unroll
        for (int q = 0; q < 8; ++q) pk[q] = (short)f2b(o[q]);
        *reinterpret_cast<short8*>(h0 + (size_t)node * CIN + c16 * 8) = pk;
    }
}

// ---------------- fused MLP v4: 2-deep prefetch in phase 2 ----------------
// 64 rows/block, 256 thr. Phase 1: 1-deep reg prefetch (as v3).
// Phase 2: K=256, ring-3 buffers on BOTH streams — A ds_read from swizzled
// LDS (120cyc latency vs 78cyc 1-deep slack) and B (w2) global (~200cyc).
// Fused epilogue: rowsum[row*4+wave] = partial w3-dot (race-free slots).

__global__ __launch_bounds__(256) void fmlp_k(
    const unsigned short* __restrict__ h0, const unsigned short* __restrict__ w1,
    const float* __restrict__ b1, const unsigned short* __restrict__ w2,
    const float* __restrict__ b2, const float* __restrict__ w3,
    float* __restrict__ rowsum, int M)
{
    __shared__ unsigned short h1s[64 * 256];   // 32 KB, xor-swizzled
    const int tid = threadIdx.x;
    const int wave = tid >> 6;
    const int lane = tid & 63;
    const int quad = lane >> 4;
    const int l16 = lane & 15;
    const int bm = blockIdx.x * 64;
    const int nc0 = wave * 64;

    f32x4 acc[4][4];
#pragma unroll
    for (int i = 0; i < 4; ++i)
#pragma unroll
        for (int j = 0; j < 4; ++j) {
            f32x4 z = {0.f, 0.f, 0.f, 0.f};
            acc[i][j] = z;
        }

    // ---- phase 1: h1 = relu(h0 @ W1^T + b1), K=128 ----
    {
        const unsigned short* pa[4];
        const unsigned short* pb[4];
#pragma unroll
        for (int t = 0; t < 4; ++t) {
            int m = bm + t * 16 + l16; if (m >= M) m = M - 1;
            pa[t] = h0 + (size_t)m * 128 + quad * 8;
            int n = nc0 + t * 16 + l16;
            pb[t] = w1 + (size_t)n * 128 + quad * 8;
        }
        short8 af[2][4], bf[2][4];
#pragma unroll
        for (int t = 0; t < 4; ++t) {
            af[0][t] = *reinterpret_cast<const short8*>(pa[t]);
            bf[0][t] = *reinterpret_cast<const short8*>(pb[t]);
        }
#pragma unroll
        for (int kt = 0; kt < 4; ++kt) {
            const int cur = kt & 1, nxt = cur ^ 1;
            if (kt < 3) {
#pragma unroll
                for (int t = 0; t < 4; ++t) {
                    af[nxt][t] = *reinterpret_cast<const short8*>(pa[t] + (kt + 1) * 32);
                    bf[nxt][t] = *reinterpret_cast<const short8*>(pb[t] + (kt + 1) * 32);
                }
            }
#pragma unroll
            for (int i = 0; i < 4; ++i)
#pragma unroll
                for (int j = 0; j < 4; ++j)
                    acc[i][j] = __builtin_amdgcn_mfma_f32_16x16x32_bf16(af[cur][i], bf[cur][j], acc[i][j], 0, 0, 0);
        }
        // relu+bias -> swizzled LDS: (row,col) at row*256 + (((col>>3)^(row&7))<<3 | (col&7))
#pragma unroll
        for (int nt = 0; nt < 4; ++nt) {
            int col = nc0 + nt * 16 + l16;
            float bv = b1[col];
            int chunk = col >> 3, rem = col & 7;
#pragma unroll
            for (int mt = 0; mt < 4; ++mt)
#pragma unroll
                for (int r = 0; r < 4; ++r) {
                    int row = mt * 16 + quad * 4 + r;
                    h1s[row * 256 + (((chunk ^ (row & 7)) << 3) | rem)] =
                        f2b(fmaxf(acc[mt][nt][r] + bv, 0.f));
                }
        }
    }
    __syncthreads();

    // ---- phase 2: h2 = relu(h1s @ W2^T + b2), K=256, ring-3 both streams ----
#pragma unroll
    for (int i = 0; i < 4; ++i)
#pragma unroll
        for (int j = 0; j < 4; ++j) {
            f32x4 z = {0.f, 0.f, 0.f, 0.f};
            acc[i][j] = z;
        }
    {
        const unsigned short* pb[4];
#pragma unroll
        for (int t = 0; t < 4; ++t) {
            int n = nc0 + t * 16 + l16;
            pb[t] = w2 + (size_t)n * 256 + quad * 8;
        }
        short8 af[3][4], bf[3][4];
#pragma unroll
        for (int t = 0; t < 4; ++t) {
            int row = t * 16 + l16;
            af[0][t] = *reinterpret_cast<const short8*>(
                &h1s[row * 256 + ((quad ^ (row & 7)) << 3)]);
            af[1][t] = *reinterpret_cast<const short8*>(
                &h1s[row * 256 + (((4 + quad) ^ (row & 7)) << 3)]);
            bf[0][t] = *reinterpret_cast<const short8*>(pb[t]);
            bf[1][t] = *reinterpret_cast<const short8*>(pb[t] + 32);
        }
#pragma unroll
        for (int kt = 0; kt < 8; ++kt) {
            const int cu = kt % 3, nx = (kt + 2) % 3;
            if (kt + 2 < 8) {
                const int c2 = (kt + 2) * 4 + quad;
#pragma unroll
                for (int t = 0; t < 4; ++t) {
                    int row = t * 16 + l16;
                    af[nx][t] = *reinterpret_cast<const short8*>(
                        &h1s[row * 256 + ((c2 ^ (row & 7)) << 3)]);
                    bf[nx][t] = *reinterpret_cast<const short8*>(pb[t] + (kt + 2) * 32);
                }
            }
#pragma unroll
            for (int i = 0; i < 4; ++i)
#pragma unroll
                for (int j = 0; j < 4; ++j)
                    acc[i][j] = __builtin_amdgcn_mfma_f32_16x16x32_bf16(af[cu][i], bf[cu][j], acc[i][j], 0, 0, 0);
        }
    }

    // ---- fused epilogue: partial w3-dot over this wave's 64 cols ----
    float part[4][4];
#pragma unroll
    for (int mt = 0; mt < 4; ++mt)
#pragma unroll
        for (int r = 0; r < 4; ++r) part[mt][r] = 0.f;
#pragma unroll
    for (int nt = 0; nt < 4; ++nt) {
        int col = nc0 + nt * 16 + l16;
        float bs = b2[col];
        float wv3 = w3[col];
#pragma unroll
        for (int mt = 0; mt < 4; ++mt)
#pragma unroll
            for (int r = 0; r < 4; ++r)
                part[mt][r] += fmaxf(acc[mt][nt][r] + bs, 0.f) * wv3;
    }
#pragma unroll
    for (int mt = 0; mt < 4; ++mt)
#pragma unroll
        for (int r = 0; r < 4; ++r) {
            float v = part[mt][r];
            v += __shfl_xor(v, 1, 64);
            v += __shfl_xor(v, 2, 64);
            v += __shfl_xor(v, 4, 64);
            v += __shfl_xor(v, 8, 64);
            part[mt][r] = v;
        }
    if (l16 == 0) {
#pragma unroll
        for (int mt = 0; mt < 4; ++mt)
#pragma unroll
            for (int r = 0; r < 4; ++r) {
                int row = bm + mt * 16 + quad * 4 + r;
                if (row < M) rowsum[(size_t)row * 4 + wave] = part[mt][r];
            }
    }
}

// ---------------- final: out[g] = b3 + sum of 80 rowsum slots ----------------

__global__ __launch_bounds__(256) void final_k(
    const float* __restrict__ rowsum, const float* __restrict__ b3,
    float* __restrict__ out)
{
    int g = blockIdx.x * 256 + threadIdx.x;
    if (g >= NGRAPH) return;
    const float4* p = reinterpret_cast<const float4*>(rowsum + (size_t)g * 80);
    float s = 0.f;
#pragma unroll
    for (int i = 0; i < 20; ++i) {
        float4 v = p[i];
        s += (v.x + v.y) + (v.z + v.w);
    }
    out[g] = s + b3[0];
}

// ---------------- launch ----------------

extern "C" void kernel_launch(void* const* d_in, const int* in_sizes, int n_in,
                              void* d_out, int out_size, void* d_ws, size_t ws_size,
                              hipStream_t stream)
{
    const float* x      = (const float*)d_in[0];
    const int*   ei     = (const int*)  d_in[1];
    const float* conv_w = (const float*)d_in[2];
    const float* conv_b = (const float*)d_in[3];
    const float* lin1_w = (const float*)d_in[4];
    const float* lin1_b = (const float*)d_in[5];
    const float* lin2_w = (const float*)d_in[6];
    const float* lin2_b = (const float*)d_in[7];
    const float* lin3_w = (const float*)d_in[8];
    const float* lin3_b = (const float*)d_in[9];
    float* out = (float*)d_out;

    // Workspace (~81 MB):
    //   xws bf16 [N*128] | h0 bf16 [N*128] | entries u32 [NB*CAP] | csr [NB*CAP]
    //   rowptr2 int2 [N] | dinv [N] | bfill [NB] | wt0/wt1/wt2 | rowsum [100096*4]
    unsigned short* xws     = (unsigned short*)d_ws;
    unsigned short* h0      = xws + (size_t)12800000;
    unsigned*       entries = (unsigned*)(h0 + (size_t)12800000);
    int*            csr     = (int*)(entries + (size_t)NB * CAP);
    int2*           rowptr2 = (int2*)(csr + (size_t)NB * CAP);
    float*          dinv    = (float*)(rowptr2 + NNODES);
    int*            bfill   = (int*)(dinv + NNODES);
    unsigned short* wt0     = (unsigned short*)(bfill + NB + 8);
    unsigned short* wt1     = wt0 + 16384;
    unsigned short* wt2     = wt1 + 32768;
    float*          rowsum  = (float*)(wt2 + 65536);

    // CSR build (fixed-capacity bucket windows)
    hipMemsetAsync(bfill, 0, NB * sizeof(int), stream);
    bin_k<<<BIN_WGS, 256, 0, stream>>>(ei, bfill, entries);
    bucket_build_k<<<NB, 256, 0, stream>>>(entries, bfill, rowptr2, csr, dinv);

    // weight conversions (one launch)
    cvt_w_k<<<(114688 + 255) / 256, 256, 0, stream>>>(conv_w, lin1_w, lin2_w, wt0, wt1, wt2);

    // gemm0: xws = (x @ conv_w) * dinv[row]
    mgemm0_k<<<(NNODES + 127) / 128, 256, 0, stream>>>(x, wt0, dinv, xws, NNODES);

    // gather + conv epilogue -> h0 bf16
    gather_k<<<(NNODES + 3) / 4, 256, 0, stream>>>(rowptr2, csr, xws, dinv, x, conv_b, h0);

    // fused MLP: gemm1 -> LDS -> gemm2 -> w3-dot -> rowsum (no h1 round-trip)
    fmlp_k<<<(NNODES + 63) / 64, 256, 0, stream>>>(h0, wt1, lin1_b, wt2, lin2_b, lin3_w,
                                                   rowsum, NNODES);

    // out[g] = b3 + sum of this graph's 80 rowsum slots
    final_k<<<(NGRAPH + 255) / 256, 256, 0, stream>>>(rowsum, lin3_b, out);
}